// Round 9
// baseline (529.022 us; speedup 1.0000x reference)
//
#include <hip/hip_runtime.h>

typedef __bf16 bf16x8 __attribute__((ext_vector_type(8)));
typedef float f32x4 __attribute__((ext_vector_type(4)));

#define Bdim 8192
#define NBATCH 16
#define NBLK (Bdim / NBATCH)     // 512 blocks
#define Nn 36
#define Cc 128
#define EPSf 1e-4f

// ---- d_ws layout (ushort elements): qk hi/lo split, v/proj single-bf16 ----
#define WS_QK_HI 0
#define WS_QK_LO 32768
#define WS_V_HI  65536
#define WS_P_HI  81920
// total 98304 ushorts = 192 KiB

// ---- per-batch LDS arena (byte offsets); 2 arenas x 40448 = 80896 -> 2 blk/CU ----
#define OFF_XH   0        // ush [48][128] swz15  x hi          (stage->B)
#define OFF_PH   12288    // ush [48][128] swz15  x+pos hi      (stage->B)
#define OFF_PL   24576    // ush [48][128] swz15  x+pos lo      (stage->B)
#define OFF_KT   0        // ush [128 c][52]      raw k3 bf16   (C->DE) over XH
#define OFF_VT   13312    // ush [128 d][52]      v bf16        (C->DE)
#define OFF_QO   27648    // ush [36][128] swz15  q3 then O     (C->DE->G)
#define OFF_MASK 39936    // f32 [48]
#define OFF_VOX  40128    // int [36]
#define OFF_INN  40272    // f32
#define AST      40448

__device__ inline uint bfh(float f) {
    __bf16 h = (__bf16)f;
    return (uint)(*(const ushort*)&h);
}
__device__ inline uint bfl(float f) {
    float hf = (float)((__bf16)f);
    __bf16 l = (__bf16)(f - hf);
    return (uint)(*(const ushort*)&l);
}
__device__ inline uint pk2h(float a, float b) { return bfh(a) | (bfh(b) << 16); }
__device__ inline uint pk2l(float a, float b) { return bfl(a) | (bfl(b) << 16); }

union U8 { bf16x8 v; uint u[4]; };

// ---------------- pre-kernel: weights -> frag-ordered bf16 in ws ----------------
__global__ __launch_bounds__(256)
void prep_frags(const float* __restrict__ qk_w, const float* __restrict__ v_w,
                const float* __restrict__ proj_w, ushort* __restrict__ ws)
{
    int e = blockIdx.x * 256 + threadIdx.x;          // 0..65535
    const float* W; int N; int idx; int hi_off; int lo_off;
    if (e < 32768)      { W = qk_w;   N = 256; hi_off = WS_QK_HI; lo_off = WS_QK_LO; idx = e; }
    else if (e < 49152) { W = v_w;    N = 128; hi_off = WS_V_HI;  lo_off = -1;       idx = e - 32768; }
    else                { W = proj_w; N = 128; hi_off = WS_P_HI;  lo_off = -1;       idx = e - 49152; }
    int j    = idx & 7;
    int lane = (idx >> 3) & 63;
    int ks   = (idx >> 9) & 3;
    int ct   = idx >> 11;
    int col  = ct * 16 + (lane & 15);
    int k    = ks * 32 + (lane >> 4) * 8 + j;
    float v  = W[k * N + col];
    ws[hi_off + idx] = (ushort)bfh(v);
    if (lo_off >= 0) ws[lo_off + idx] = (ushort)bfl(v);
}

// -------- main kernel: 512 thr (8 waves), persistent loop over 16 batches --------
__global__ __launch_bounds__(512, 4)
void fla_mfma(const float* __restrict__ x, const float* __restrict__ pos,
              const float* __restrict__ mask, const float* __restrict__ qk_b,
              const float* __restrict__ v_b, const float* __restrict__ proj_b,
              const int* __restrict__ vox, const ushort* __restrict__ ws,
              float* __restrict__ out)
{
    __shared__ __align__(16) char lds[2][AST];
    const int t = threadIdx.x;
    const int lane = t & 63;
    const int wv = t >> 6;                           // 8 waves
    const int  rsel = lane & 15;
    const int  grp  = lane >> 4;
    const uint kgrp = (uint)grp * 8u;
    const uint sw   = ((uint)rsel) << 4;             // row&15 swizzle on frag reads

    const int base = blockIdx.x * NBATCH;

    // ---------------- staging registers (batch in flight) ----------------
    float4 sx0, sx1, sx2, sp0, sp1, sp2;
    float  mv = 0.f;
    int    vx = 0;

    auto stage_load = [&](int bb) {
        const float* xg = x + (size_t)bb * (Nn * Cc);
        const float* pg = pos + (size_t)bb * (Nn * Cc);
        {
            int n = t >> 5, c4 = (t & 31) << 2;
            sx0 = *(const float4*)(xg + n * Cc + c4);
            sp0 = *(const float4*)(pg + n * Cc + c4);
        }
        {
            int idx = t + 512;
            int n = idx >> 5, c4 = (idx & 31) << 2;
            sx1 = *(const float4*)(xg + n * Cc + c4);
            sp1 = *(const float4*)(pg + n * Cc + c4);
        }
        if (t < 128) {
            int idx = t + 1024;
            int n = idx >> 5, c4 = (idx & 31) << 2;
            sx2 = *(const float4*)(xg + n * Cc + c4);
            sp2 = *(const float4*)(pg + n * Cc + c4);
        }
        mv = 0.f;
        if (t < Nn) mv = mask[(size_t)bb * Nn + t];
        if (t >= 64 && t < 64 + Nn) vx = vox[(size_t)bb * Nn + (t - 64)];
    };

    auto stage_write = [&](char* L) {
        auto put = [&](int idx, float4 xv, float4 pv) {
            int n = idx >> 5, c4 = (idx & 31) << 2;
            float s0 = xv.x + pv.x, s1 = xv.y + pv.y;
            float s2 = xv.z + pv.z, s3 = xv.w + pv.w;
            uint ba = (uint)n * 256u + (((uint)(c4 * 2)) ^ (((uint)n & 15u) << 4));
            *(uint2*)(L + OFF_XH + ba) = make_uint2(pk2h(xv.x, xv.y), pk2h(xv.z, xv.w));
            *(uint2*)(L + OFF_PH + ba) = make_uint2(pk2h(s0, s1), pk2h(s2, s3));
            *(uint2*)(L + OFF_PL + ba) = make_uint2(pk2l(s0, s1), pk2l(s2, s3));
        };
        put(t, sx0, sp0);
        put(t + 512, sx1, sp1);
        if (t < 128) put(t + 1024, sx2, sp2);
        if (t < 48) ((float*)(L + OFF_MASK))[t] = (t < Nn) ? mv : 0.f;
        if (t >= 64 && t < 64 + Nn) ((int*)(L + OFF_VOX))[t - 64] = vx;
        if (wv == 0) {                                // inn via wave-0 shfl reduce
            float s = mv;                             // lanes >=36 hold 0
            s += __shfl_xor(s, 1);  s += __shfl_xor(s, 2);
            s += __shfl_xor(s, 4);  s += __shfl_xor(s, 8);
            s += __shfl_xor(s, 16); s += __shfl_xor(s, 32);
            if (lane == 0) *(float*)(L + OFF_INN) = 1.f / (s + EPSf);
        }
    };

    // ---------------- prologue: stage batch 0 into arena 0 ----------------
    stage_load(base);
    stage_write(lds[0]);
    __syncthreads();

    #pragma unroll 2
    for (int i = 0; i < NBATCH; ++i) {
        char* L  = lds[i & 1];
        char* Ln = lds[(i + 1) & 1];

        // ---------- Phase B: qk GEMM (split-bf16, 2 tiles) + v GEMM (1 tile) -------
        f32x4 accQ[3][2];
        f32x4 accV[3];
        #pragma unroll
        for (int rt = 0; rt < 3; ++rt) {
            accV[rt] = (f32x4){0.f, 0.f, 0.f, 0.f};
            accQ[rt][0] = (f32x4){0.f, 0.f, 0.f, 0.f};
            accQ[rt][1] = (f32x4){0.f, 0.f, 0.f, 0.f};
        }
        #pragma unroll
        for (int ks = 0; ks < 4; ++ks) {              // v: A = x(hi) only
            uint ka = (((uint)(ks * 32) + kgrp) * 2u) ^ sw;
            bf16x8 xh[3];
            #pragma unroll
            for (int rt = 0; rt < 3; ++rt)
                xh[rt] = *(const bf16x8*)(L + OFF_XH + (uint)(rt * 16 + rsel) * 256u + ka);
            int f = ((wv * 4 + ks) * 64 + lane) * 8;
            bf16x8 bvh = *(const bf16x8*)(ws + WS_V_HI + f);
            #pragma unroll
            for (int rt = 0; rt < 3; ++rt)
                accV[rt] = __builtin_amdgcn_mfma_f32_16x16x32_bf16(xh[rt], bvh, accV[rt], 0, 0, 0);
        }
        #pragma unroll
        for (int ks = 0; ks < 4; ++ks) {              // qk: split 3-product
            uint ka = (((uint)(ks * 32) + kgrp) * 2u) ^ sw;
            bf16x8 ph[3], pl[3];
            #pragma unroll
            for (int rt = 0; rt < 3; ++rt) {
                uint ba = (uint)(rt * 16 + rsel) * 256u + ka;
                ph[rt] = *(const bf16x8*)(L + OFF_PH + ba);
                pl[rt] = *(const bf16x8*)(L + OFF_PL + ba);
            }
            #pragma unroll
            for (int ci = 0; ci < 2; ++ci) {
                int f = (((wv * 2 + ci) * 4 + ks) * 64 + lane) * 8;
                bf16x8 bh = *(const bf16x8*)(ws + WS_QK_HI + f);
                bf16x8 bl = *(const bf16x8*)(ws + WS_QK_LO + f);
                #pragma unroll
                for (int rt = 0; rt < 3; ++rt) {
                    accQ[rt][ci] = __builtin_amdgcn_mfma_f32_16x16x32_bf16(ph[rt], bh, accQ[rt][ci], 0, 0, 0);
                    accQ[rt][ci] = __builtin_amdgcn_mfma_f32_16x16x32_bf16(ph[rt], bl, accQ[rt][ci], 0, 0, 0);
                    accQ[rt][ci] = __builtin_amdgcn_mfma_f32_16x16x32_bf16(pl[rt], bh, accQ[rt][ci], 0, 0, 0);
                }
            }
        }
        if (i + 1 < NBATCH) stage_load(base + i + 1);   // in flight across C/DE/G
        __syncthreads();   // staging area of L dead; C may overwrite

        // ---------- Phase C: epilogues -> VT, QO(raw q3), KT(raw k3) ---------------
        {
            const float* sM = (const float*)(L + OFF_MASK);
            {   // v: +bias -> bf16 -> VT[d=col][n] (stride 52); rows>=36 forced 0
                int colv = wv * 16 + rsel;
                float vb = v_b[colv];
                #pragma unroll
                for (int rt = 0; rt < 3; ++rt) {
                    float a0 = accV[rt][0] + vb, a1 = accV[rt][1] + vb;
                    float a2 = accV[rt][2] + vb, a3 = accV[rt][3] + vb;
                    if (rt == 2 && grp != 0) { a0 = 0.f; a1 = 0.f; a2 = 0.f; a3 = 0.f; }
                    uint addr = OFF_VT + (uint)(colv * 52 + rt * 16 + grp * 4) * 2u;
                    *(uint2*)(L + addr) = make_uint2(pk2h(a0, a1), pk2h(a2, a3));
                }
            }
            if (wv < 4) {       // q: +bias, cube -> QO scatter (rows<36)
                #pragma unroll
                for (int ci = 0; ci < 2; ++ci) {
                    int colq = (wv * 2 + ci) * 16 + rsel;
                    float qb = qk_b[colq];
                    uint cb2 = (uint)(colq * 2);
                    #pragma unroll
                    for (int rt = 0; rt < 3; ++rt) {
                        #pragma unroll
                        for (int r = 0; r < 4; ++r) {
                            int row = rt * 16 + grp * 4 + r;
                            if (row < Nn) {
                                float q1 = accQ[rt][ci][r] + qb;
                                float q3 = q1 * q1 * q1;
                                uint ba = (uint)row * 256u + (cb2 ^ (((uint)row & 15u) << 4));
                                *(ushort*)(L + OFF_QO + ba) = (ushort)bfh(q3);
                            }
                        }
                    }
                }
            } else {            // k: +bias, *mask, cube -> KT[c=col][n]; rows>=36 -> 0
                #pragma unroll
                for (int ci = 0; ci < 2; ++ci) {
                    int colk = ((wv - 4) * 2 + ci) * 16 + rsel;
                    float kb = qk_b[Cc + colk];
                    #pragma unroll
                    for (int rt = 0; rt < 3; ++rt) {
                        float k3v[4];
                        #pragma unroll
                        for (int r = 0; r < 4; ++r) {
                            int row = rt * 16 + grp * 4 + r;
                            float k1 = (accQ[rt][ci][r] + kb) * sM[row];
                            float k3 = k1 * k1 * k1;
                            k3v[r] = (rt == 2 && grp != 0) ? 0.f : k3;
                        }
                        uint addr = OFF_KT + (uint)(colk * 52 + rt * 16 + grp * 4) * 2u;
                        *(uint2*)(L + addr) = make_uint2(pk2h(k3v[0], k3v[1]), pk2h(k3v[2], k3v[3]));
                    }
                }
            }
        }
        __syncthreads();

        // ---------- Phase DE: head h=wv; kv in registers; out -> QO ----------------
        {
            uint bkvU[4];
            {
                int col16 = wv * 16 + rsel;              // c (A-row) and d (B-col)
                uint a0 = OFF_KT + (uint)(col16 * 52 + grp * 8) * 2u;
                uint b0 = OFF_VT + (uint)(col16 * 52 + grp * 8) * 2u;
                bf16x8 kA0 = *(const bf16x8*)(L + a0);
                bf16x8 vB0 = *(const bf16x8*)(L + b0);
                U8 kA1, vB1;
                kA1.u[0] = kA1.u[1] = kA1.u[2] = kA1.u[3] = 0u;
                vB1.u[0] = vB1.u[1] = vB1.u[2] = vB1.u[3] = 0u;
                if (grp < 2) {                           // n = 32 + grp*8 .. +7
                    kA1.v = *(const bf16x8*)(L + a0 + 64);
                    vB1.v = *(const bf16x8*)(L + b0 + 64);
                }
                float s = 0.f;
                #pragma unroll
                for (int j = 0; j < 8; ++j) { float q = (float)kA0[j]; s += q * q; }
                #pragma unroll
                for (int j = 0; j < 8; ++j) { float q = (float)kA1.v[j]; s += q * q; }
                s += __shfl_xor(s, 16);
                s += __shfl_xor(s, 32);
                float invkn = 1.f / (EPSf + sqrtf(s));

                f32x4 kvacc = (f32x4){0.f, 0.f, 0.f, 0.f};
                kvacc = __builtin_amdgcn_mfma_f32_16x16x32_bf16(kA0, vB0, kvacc, 0, 0, 0);
                kvacc = __builtin_amdgcn_mfma_f32_16x16x32_bf16(kA1.v, vB1.v, kvacc, 0, 0, 0);
                #pragma unroll
                for (int r = 0; r < 4; ++r)
                    kvacc[r] *= __shfl(invkn, grp * 4 + r);

                float bv[8];
                #pragma unroll
                for (int j = 0; j < 8; ++j)
                    bv[j] = __shfl(kvacc[j & 3], rsel + 16 * (2 * grp + (j >> 2)));
                if (grp >= 2) {
                    #pragma unroll
                    for (int j = 0; j < 8; ++j) bv[j] = 0.f;
                }
                bkvU[0] = pk2h(bv[0], bv[1]);
                bkvU[1] = pk2h(bv[2], bv[3]);
                bkvU[2] = pk2h(bv[4], bv[5]);
                bkvU[3] = pk2h(bv[6], bv[7]);
            }
            float inn = *(const float*)(L + OFF_INN);
            U8 aq[3];
            uint cb = (uint)(wv * 32 + grp * 16);
            #pragma unroll
            for (int rt = 0; rt < 3; ++rt) {
                int row = rt * 16 + rsel;
                aq[rt].u[0] = aq[rt].u[1] = aq[rt].u[2] = aq[rt].u[3] = 0u;
                if (grp < 2 && row < Nn)
                    aq[rt].v = *(const bf16x8*)(L + OFF_QO + (uint)row * 256u + (cb ^ sw));
            }
            f32x4 oacc[3];
            float invn[3];
            U8 bkv;
            bkv.u[0] = bkvU[0]; bkv.u[1] = bkvU[1]; bkv.u[2] = bkvU[2]; bkv.u[3] = bkvU[3];
            #pragma unroll
            for (int rt = 0; rt < 3; ++rt) {
                float s = 0.f;
                #pragma unroll
                for (int j = 0; j < 8; ++j) { float q = (float)aq[rt].v[j]; s += q * q; }
                s += __shfl_xor(s, 16);               // lanes 0..31 hold full row norm
                invn[rt] = 1.f / (EPSf + sqrtf(s));
                f32x4 o = (f32x4){0.f, 0.f, 0.f, 0.f};
                o = __builtin_amdgcn_mfma_f32_16x16x32_bf16(aq[rt].v, bkv.v, o, 0, 0, 0);
                oacc[rt] = o;
            }
            uint cb2 = (uint)((wv * 16 + rsel) * 2);
            #pragma unroll
            for (int rt = 0; rt < 3; ++rt) {
                #pragma unroll
                for (int r = 0; r < 4; ++r) {
                    int rr = grp * 4 + r;
                    int row = rt * 16 + rr;
                    if (row < Nn) {
                        float fac = __shfl(invn[rt], rr) * inn;
                        float val = oacc[rt][r] * fac;
                        uint ba = (uint)row * 256u + (cb2 ^ (((uint)row & 15u) << 4));
                        *(ushort*)(L + OFF_QO + ba) = (ushort)bfh(val);
                    }
                }
            }
        }
        __syncthreads();

        // ---------- Phase G: proj GEMM (1 tile/wave) + voxel scatter ---------------
        {
            f32x4 accP[3];
            #pragma unroll
            for (int rt = 0; rt < 3; ++rt) accP[rt] = (f32x4){0.f, 0.f, 0.f, 0.f};
            #pragma unroll
            for (int ks = 0; ks < 4; ++ks) {
                uint ka = (((uint)(ks * 32) + kgrp) * 2u) ^ sw;
                bf16x8 oa[3];
                #pragma unroll
                for (int rt = 0; rt < 3; ++rt)
                    oa[rt] = *(const bf16x8*)(L + OFF_QO + (uint)(rt * 16 + rsel) * 256u + ka);
                int f = ((wv * 4 + ks) * 64 + lane) * 8;
                bf16x8 bp = *(const bf16x8*)(ws + WS_P_HI + f);
                #pragma unroll
                for (int rt = 0; rt < 3; ++rt)
                    accP[rt] = __builtin_amdgcn_mfma_f32_16x16x32_bf16(oa[rt], bp, accP[rt], 0, 0, 0);
            }
            const int* sVx = (const int*)(L + OFF_VOX);
            int col = wv * 16 + rsel;
            float pb = proj_b[col];
            #pragma unroll
            for (int rt = 0; rt < 3; ++rt) {
                #pragma unroll
                for (int r = 0; r < 4; ++r) {
                    int row = rt * 16 + grp * 4 + r;
                    if (row < Nn)
                        out[(size_t)sVx[row] * Cc + col] = accP[rt][r] + pb;
                }
            }
        }
        if (i + 1 < NBATCH) stage_write(Ln);
        __syncthreads();
    }
}

extern "C" void kernel_launch(void* const* d_in, const int* in_sizes, int n_in,
                              void* d_out, int out_size, void* d_ws, size_t ws_size,
                              hipStream_t stream) {
    (void)in_sizes; (void)n_in; (void)out_size; (void)ws_size;
    const float* x      = (const float*)d_in[0];
    const float* pos    = (const float*)d_in[1];
    const float* mask   = (const float*)d_in[2];
    const float* qk_w   = (const float*)d_in[3];
    const float* qk_b   = (const float*)d_in[4];
    const float* v_w    = (const float*)d_in[5];
    const float* v_b    = (const float*)d_in[6];
    const float* proj_w = (const float*)d_in[7];
    const float* proj_b = (const float*)d_in[8];
    // d_in[9] = coords (unused)
    const int*   vox    = (const int*)d_in[10];
    ushort* ws = (ushort*)d_ws;            // 192 KiB scratch used
    float* outp = (float*)d_out;

    hipLaunchKernelGGL(prep_frags, dim3(256), dim3(256), 0, stream, qk_w, v_w, proj_w, ws);
    hipLaunchKernelGGL(fla_mfma, dim3(NBLK), dim3(512), 0, stream,
                       x, pos, mask, qk_b, v_b, proj_b, vox, ws, outp);
}

// Round 10
// 440.418 us; speedup vs baseline: 1.2012x; 1.2012x over previous
//
#include <hip/hip_runtime.h>

typedef __bf16 bf16x8 __attribute__((ext_vector_type(8)));
typedef float f32x4 __attribute__((ext_vector_type(4)));

#define Bdim 8192
#define NBLK 512
#define NBATCH (Bdim / NBLK)    // 16 batches per block
#define Nn 36
#define Cc 128
#define EPSf 1e-4f

// ---- d_ws layout (ushort elements): qk hi/lo split, v/proj single-bf16 ----
#define WS_QK_HI 0
#define WS_QK_LO 32768
#define WS_V_HI  65536
#define WS_P_HI  81920

// ---- LDS arena (bytes); 75984 -> 2 blocks/CU (151968 <= 163840) ----
#define OFF_XH   0        // ush [48][128] swz15  x hi        (stage -> B)
#define OFF_PH   12288    // ush [48][128] swz15  x+pos hi    (stage -> B)
#define OFF_PL   24576    // ush [48][128] swz15  x+pos lo    (stage -> B)
#define OFF_KT   36864    // ush [128 c][52]      raw k3 bf16 (wave-private cols)
#define OFF_VT   50176    // ush [128 d][52]      v bf16      (wave-private cols)
#define OFF_QO   63488    // ush [48][128] swz15  q3 then O   (q3/O wave-private cols; G reads all)
#define OFF_MASK 75776    // f32 [48]
#define OFF_INN  75968    // f32
#define LDS_BYTES 75984

__device__ inline uint bfh(float f) {
    __bf16 h = (__bf16)f;
    return (uint)(*(const ushort*)&h);
}
__device__ inline uint bfl(float f) {
    float hf = (float)((__bf16)f);
    __bf16 l = (__bf16)(f - hf);
    return (uint)(*(const ushort*)&l);
}
__device__ inline uint pk2h(float a, float b) { return bfh(a) | (bfh(b) << 16); }
__device__ inline uint pk2l(float a, float b) { return bfl(a) | (bfl(b) << 16); }

union U8 { bf16x8 v; uint u[4]; };

// ---------------- pre-kernel: weights -> frag-ordered bf16 in ws ----------------
__global__ __launch_bounds__(256)
void prep_frags(const float* __restrict__ qk_w, const float* __restrict__ v_w,
                const float* __restrict__ proj_w, ushort* __restrict__ ws)
{
    int e = blockIdx.x * 256 + threadIdx.x;          // 0..65535
    const float* W; int N; int idx; int hi_off; int lo_off;
    if (e < 32768)      { W = qk_w;   N = 256; hi_off = WS_QK_HI; lo_off = WS_QK_LO; idx = e; }
    else if (e < 49152) { W = v_w;    N = 128; hi_off = WS_V_HI;  lo_off = -1;       idx = e - 32768; }
    else                { W = proj_w; N = 128; hi_off = WS_P_HI;  lo_off = -1;       idx = e - 49152; }
    int j    = idx & 7;
    int lane = (idx >> 3) & 63;
    int ks   = (idx >> 9) & 3;
    int ct   = idx >> 11;
    int col  = ct * 16 + (lane & 15);
    int k    = ks * 32 + (lane >> 4) * 8 + j;
    float v  = W[k * N + col];
    ws[hi_off + idx] = (ushort)bfh(v);
    if (lo_off >= 0) ws[lo_off + idx] = (ushort)bfl(v);
}

// -------- main: 512 thr = 8 waves; wave h owns head h end-to-end; 16 batches --------
__global__ __launch_bounds__(512, 4)
void fla_mfma(const float* __restrict__ x, const float* __restrict__ pos,
              const float* __restrict__ mask, const float* __restrict__ qk_b,
              const float* __restrict__ v_b, const float* __restrict__ proj_b,
              const int* __restrict__ vox, const ushort* __restrict__ ws,
              float* __restrict__ out)
{
    __shared__ __align__(16) char lds[LDS_BYTES];
    const int t = threadIdx.x;
    const int lane = t & 63;
    const int wv = t >> 6;                           // wave = head
    const int  rsel = lane & 15;
    const int  grp  = lane >> 4;
    const uint kgrp = (uint)grp * 8u;
    const uint sw   = ((uint)rsel) << 4;             // row&15 swizzle on frag reads

    const int base = blockIdx.x * NBATCH;

    // hoisted per-lane constants (L1-resident scalar loads, once per block)
    const float qb = qk_b[wv * 16 + rsel];
    const float kb = qk_b[Cc + wv * 16 + rsel];
    const float vb = v_b[wv * 16 + rsel];
    const float pb = proj_b[wv * 16 + rsel];
    const int c16 = wv * 16 + rsel;

    // staging registers (next batch in flight)
    float4 sx0, sx1, sx2, sp0, sp1, sp2;
    float  mv = 0.f;

    auto stage_load = [&](int bb) {
        const float* xg = x + (size_t)bb * (Nn * Cc);
        const float* pg = pos + (size_t)bb * (Nn * Cc);
        {
            int n = t >> 5, c4 = (t & 31) << 2;
            sx0 = *(const float4*)(xg + n * Cc + c4);
            sp0 = *(const float4*)(pg + n * Cc + c4);
        }
        {
            int idx = t + 512;
            int n = idx >> 5, c4 = (idx & 31) << 2;
            sx1 = *(const float4*)(xg + n * Cc + c4);
            sp1 = *(const float4*)(pg + n * Cc + c4);
        }
        if (t < 128) {
            int idx = t + 1024;
            int n = idx >> 5, c4 = (idx & 31) << 2;
            sx2 = *(const float4*)(xg + n * Cc + c4);
            sp2 = *(const float4*)(pg + n * Cc + c4);
        }
        mv = (t < Nn) ? mask[(size_t)bb * Nn + t] : 0.f;
    };

    auto stage_write = [&]() {
        auto put = [&](int idx, float4 xv, float4 pv) {
            int n = idx >> 5, c4 = (idx & 31) << 2;
            float s0 = xv.x + pv.x, s1 = xv.y + pv.y;
            float s2 = xv.z + pv.z, s3 = xv.w + pv.w;
            uint ba = (uint)n * 256u + (((uint)(c4 * 2)) ^ (((uint)n & 15u) << 4));
            *(uint2*)(lds + OFF_XH + ba) = make_uint2(pk2h(xv.x, xv.y), pk2h(xv.z, xv.w));
            *(uint2*)(lds + OFF_PH + ba) = make_uint2(pk2h(s0, s1), pk2h(s2, s3));
            *(uint2*)(lds + OFF_PL + ba) = make_uint2(pk2l(s0, s1), pk2l(s2, s3));
        };
        put(t, sx0, sp0);
        put(t + 512, sx1, sp1);
        if (t < 128) put(t + 1024, sx2, sp2);
        if (t < 48) ((float*)(lds + OFF_MASK))[t] = (t < Nn) ? mv : 0.f;
        if (wv == 0) {                                 // inn via wave-0 butterfly
            float s = mv;                              // lanes >= 36 hold 0
            s += __shfl_xor(s, 1);  s += __shfl_xor(s, 2);
            s += __shfl_xor(s, 4);  s += __shfl_xor(s, 8);
            s += __shfl_xor(s, 16); s += __shfl_xor(s, 32);
            if (lane == 0) *(float*)(lds + OFF_INN) = 1.f / (s + EPSf);
        }
    };

    // prologue: stage batch 0
    stage_load(base);
    stage_write();
    __syncthreads();

    #pragma unroll 1
    for (int i = 0; i < NBATCH; ++i) {
        // ---------------- B_qk: q and k column-tiles of head wv (split-bf16) --------
        f32x4 accQ[3], accK[3];
        #pragma unroll
        for (int rt = 0; rt < 3; ++rt) {
            accQ[rt] = (f32x4){0.f, 0.f, 0.f, 0.f};
            accK[rt] = (f32x4){0.f, 0.f, 0.f, 0.f};
        }
        #pragma unroll
        for (int ks = 0; ks < 4; ++ks) {
            uint ka = (((uint)(ks * 32) + kgrp) * 2u) ^ sw;
            bf16x8 ph[3], pl[3];
            #pragma unroll
            for (int rt = 0; rt < 3; ++rt) {
                uint ba = (uint)(rt * 16 + rsel) * 256u + ka;
                ph[rt] = *(const bf16x8*)(lds + OFF_PH + ba);
                pl[rt] = *(const bf16x8*)(lds + OFF_PL + ba);
            }
            int fq = ((wv * 4 + ks) * 64 + lane) * 8;
            int fk = (((8 + wv) * 4 + ks) * 64 + lane) * 8;
            bf16x8 bqh = *(const bf16x8*)(ws + WS_QK_HI + fq);
            bf16x8 bql = *(const bf16x8*)(ws + WS_QK_LO + fq);
            bf16x8 bkh = *(const bf16x8*)(ws + WS_QK_HI + fk);
            bf16x8 bkl = *(const bf16x8*)(ws + WS_QK_LO + fk);
            #pragma unroll
            for (int rt = 0; rt < 3; ++rt) {
                accQ[rt] = __builtin_amdgcn_mfma_f32_16x16x32_bf16(ph[rt], bqh, accQ[rt], 0, 0, 0);
                accQ[rt] = __builtin_amdgcn_mfma_f32_16x16x32_bf16(ph[rt], bql, accQ[rt], 0, 0, 0);
                accQ[rt] = __builtin_amdgcn_mfma_f32_16x16x32_bf16(pl[rt], bqh, accQ[rt], 0, 0, 0);
                accK[rt] = __builtin_amdgcn_mfma_f32_16x16x32_bf16(ph[rt], bkh, accK[rt], 0, 0, 0);
                accK[rt] = __builtin_amdgcn_mfma_f32_16x16x32_bf16(ph[rt], bkl, accK[rt], 0, 0, 0);
                accK[rt] = __builtin_amdgcn_mfma_f32_16x16x32_bf16(pl[rt], bkh, accK[rt], 0, 0, 0);
            }
        }

        // ---------------- C_qk: q3 -> QO (scatter), raw k3 -> KT (own cols) ---------
        {
            const float* sM = (const float*)(lds + OFF_MASK);
            uint cb2 = (uint)(c16 * 2);
            #pragma unroll
            for (int rt = 0; rt < 3; ++rt) {
                #pragma unroll
                for (int r = 0; r < 4; ++r) {
                    int row = rt * 16 + grp * 4 + r;
                    if (row < Nn) {
                        float q1 = accQ[rt][r] + qb;
                        float q3 = q1 * q1 * q1;
                        uint ba = (uint)row * 256u + (cb2 ^ (((uint)row & 15u) << 4));
                        *(ushort*)(lds + OFF_QO + ba) = (ushort)bfh(q3);
                    }
                }
            }
            #pragma unroll
            for (int rt = 0; rt < 3; ++rt) {
                float k3v[4];
                #pragma unroll
                for (int r = 0; r < 4; ++r) {
                    int row = rt * 16 + grp * 4 + r;
                    float k1 = (accK[rt][r] + kb) * sM[row];
                    float k3 = k1 * k1 * k1;
                    k3v[r] = (rt == 2 && grp != 0) ? 0.f : k3;   // pad rows exact 0
                }
                uint addr = OFF_KT + (uint)(c16 * 52 + rt * 16 + grp * 4) * 2u;
                *(uint2*)(lds + addr) = make_uint2(pk2h(k3v[0], k3v[1]), pk2h(k3v[2], k3v[3]));
            }
        }

        // ---------------- B_v: v column-tile of head wv (single-bf16) ---------------
        f32x4 accV[3];
        #pragma unroll
        for (int rt = 0; rt < 3; ++rt) accV[rt] = (f32x4){0.f, 0.f, 0.f, 0.f};
        #pragma unroll
        for (int ks = 0; ks < 4; ++ks) {
            uint ka = (((uint)(ks * 32) + kgrp) * 2u) ^ sw;
            bf16x8 xh[3];
            #pragma unroll
            for (int rt = 0; rt < 3; ++rt)
                xh[rt] = *(const bf16x8*)(lds + OFF_XH + (uint)(rt * 16 + rsel) * 256u + ka);
            int fv = ((wv * 4 + ks) * 64 + lane) * 8;
            bf16x8 bvh = *(const bf16x8*)(ws + WS_V_HI + fv);
            #pragma unroll
            for (int rt = 0; rt < 3; ++rt)
                accV[rt] = __builtin_amdgcn_mfma_f32_16x16x32_bf16(xh[rt], bvh, accV[rt], 0, 0, 0);
        }

        if (i + 1 < NBATCH) stage_load(base + i + 1);   // in flight across C_v/D/E

        // ---------------- C_v: v(+bias) -> VT (own cols) ----------------------------
        #pragma unroll
        for (int rt = 0; rt < 3; ++rt) {
            float a0 = accV[rt][0] + vb, a1 = accV[rt][1] + vb;
            float a2 = accV[rt][2] + vb, a3 = accV[rt][3] + vb;
            if (rt == 2 && grp != 0) { a0 = 0.f; a1 = 0.f; a2 = 0.f; a3 = 0.f; }
            uint addr = OFF_VT + (uint)(c16 * 52 + rt * 16 + grp * 4) * 2u;
            *(uint2*)(lds + addr) = make_uint2(pk2h(a0, a1), pk2h(a2, a3));
        }

        // ---------------- D: kv-hat = invkn[c]*(k3^T @ v), all wave-private ---------
        f32x4 kvacc;
        {
            uint a0 = OFF_KT + (uint)(c16 * 52 + grp * 8) * 2u;
            uint b0 = OFF_VT + (uint)(c16 * 52 + grp * 8) * 2u;
            bf16x8 kA0 = *(const bf16x8*)(lds + a0);
            bf16x8 vB0 = *(const bf16x8*)(lds + b0);
            U8 kA1, vB1;
            kA1.u[0] = kA1.u[1] = kA1.u[2] = kA1.u[3] = 0u;
            vB1.u[0] = vB1.u[1] = vB1.u[2] = vB1.u[3] = 0u;
            if (grp < 2) {                               // n = 32 + grp*8 .. +7
                kA1.v = *(const bf16x8*)(lds + a0 + 64);
                vB1.v = *(const bf16x8*)(lds + b0 + 64);
            }
            float s = 0.f;
            #pragma unroll
            for (int j = 0; j < 8; ++j) { float q = (float)kA0[j]; s += q * q; }
            #pragma unroll
            for (int j = 0; j < 8; ++j) { float q = (float)kA1.v[j]; s += q * q; }
            s += __shfl_xor(s, 16);
            s += __shfl_xor(s, 32);
            float invkn = 1.f / (EPSf + sqrtf(s));

            kvacc = (f32x4){0.f, 0.f, 0.f, 0.f};
            kvacc = __builtin_amdgcn_mfma_f32_16x16x32_bf16(kA0, vB0, kvacc, 0, 0, 0);
            kvacc = __builtin_amdgcn_mfma_f32_16x16x32_bf16(kA1.v, vB1.v, kvacc, 0, 0, 0);
            #pragma unroll
            for (int r = 0; r < 4; ++r)
                kvacc[r] *= __shfl(invkn, grp * 4 + r);
        }

        // ---------------- E: out = invn[row]*inn * (q3 @ kv-hat) -> O (own cols) ----
        {
            float bv[8];
            #pragma unroll
            for (int j = 0; j < 8; ++j)
                bv[j] = __shfl(kvacc[j & 3], rsel + 16 * (2 * grp + (j >> 2)));
            if (grp >= 2) {
                #pragma unroll
                for (int j = 0; j < 8; ++j) bv[j] = 0.f;
            }
            U8 bkv;
            bkv.u[0] = pk2h(bv[0], bv[1]); bkv.u[1] = pk2h(bv[2], bv[3]);
            bkv.u[2] = pk2h(bv[4], bv[5]); bkv.u[3] = pk2h(bv[6], bv[7]);

            float inn = *(const float*)(lds + OFF_INN);
            U8 aq[3];
            #pragma unroll
            for (int rt = 0; rt < 3; ++rt) {
                int row = rt * 16 + rsel;
                aq[rt].u[0] = aq[rt].u[1] = aq[rt].u[2] = aq[rt].u[3] = 0u;
                if (grp < 2 && row < Nn)
                    aq[rt].v = *(const bf16x8*)(lds + OFF_QO + (uint)row * 256u +
                                                (((uint)(wv * 32 + grp * 16)) ^ sw));
            }
            f32x4 oacc[3];
            float invn[3];
            #pragma unroll
            for (int rt = 0; rt < 3; ++rt) {
                float s = 0.f;
                #pragma unroll
                for (int j = 0; j < 8; ++j) { float q = (float)aq[rt].v[j]; s += q * q; }
                s += __shfl_xor(s, 16);                  // lanes 0..15 hold full sum
                invn[rt] = 1.f / (EPSf + sqrtf(s));
                f32x4 o = (f32x4){0.f, 0.f, 0.f, 0.f};
                o = __builtin_amdgcn_mfma_f32_16x16x32_bf16(aq[rt].v, bkv.v, o, 0, 0, 0);
                oacc[rt] = o;
            }
            uint cb2 = (uint)(c16 * 2);
            #pragma unroll
            for (int rt = 0; rt < 3; ++rt) {
                #pragma unroll
                for (int r = 0; r < 4; ++r) {
                    int rr = grp * 4 + r;
                    int row = rt * 16 + rr;
                    if (row < Nn) {
                        float fac = __shfl(invn[rt], rr) * inn;
                        float val = oacc[rt][r] * fac;
                        uint ba = (uint)row * 256u + (cb2 ^ (((uint)row & 15u) << 4));
                        *(ushort*)(lds + OFF_QO + ba) = (ushort)bfh(val);
                    }
                }
            }
        }
        __syncthreads();                                  // O complete for all heads

        // ---------------- G: proj GEMM (own out-cols, reads all O) + scatter --------
        {
            f32x4 accP[3];
            #pragma unroll
            for (int rt = 0; rt < 3; ++rt) accP[rt] = (f32x4){0.f, 0.f, 0.f, 0.f};
            #pragma unroll
            for (int ks = 0; ks < 4; ++ks) {
                uint ka = (((uint)(ks * 32) + kgrp) * 2u) ^ sw;
                bf16x8 oa[3];
                #pragma unroll
                for (int rt = 0; rt < 3; ++rt)
                    oa[rt] = *(const bf16x8*)(lds + OFF_QO + (uint)(rt * 16 + rsel) * 256u + ka);
                int fp = ((wv * 4 + ks) * 64 + lane) * 8;
                bf16x8 bp = *(const bf16x8*)(ws + WS_P_HI + fp);
                #pragma unroll
                for (int rt = 0; rt < 3; ++rt)
                    accP[rt] = __builtin_amdgcn_mfma_f32_16x16x32_bf16(oa[rt], bp, accP[rt], 0, 0, 0);
            }
            const int* voxb = vox + (size_t)(base + i) * Nn;   // vox via global (L1/L2)
            #pragma unroll
            for (int rt = 0; rt < 3; ++rt) {
                #pragma unroll
                for (int r = 0; r < 4; ++r) {
                    int row = rt * 16 + grp * 4 + r;
                    if (row < Nn)
                        out[(size_t)voxb[row] * Cc + c16] = accP[rt][r] + pb;
                }
            }
        }
        if (i + 1 < NBATCH) stage_write();                // next batch into staging
        __syncthreads();                                  // staging ready / O free
    }
}

extern "C" void kernel_launch(void* const* d_in, const int* in_sizes, int n_in,
                              void* d_out, int out_size, void* d_ws, size_t ws_size,
                              hipStream_t stream) {
    (void)in_sizes; (void)n_in; (void)out_size; (void)ws_size;
    const float* x      = (const float*)d_in[0];
    const float* pos    = (const float*)d_in[1];
    const float* mask   = (const float*)d_in[2];
    const float* qk_w   = (const float*)d_in[3];
    const float* qk_b   = (const float*)d_in[4];
    const float* v_w    = (const float*)d_in[5];
    const float* v_b    = (const float*)d_in[6];
    const float* proj_w = (const float*)d_in[7];
    const float* proj_b = (const float*)d_in[8];
    // d_in[9] = coords (unused)
    const int*   vox    = (const int*)d_in[10];
    ushort* ws = (ushort*)d_ws;            // 192 KiB scratch used
    float* outp = (float*)d_out;

    hipLaunchKernelGGL(prep_frags, dim3(256), dim3(256), 0, stream, qk_w, v_w, proj_w, ws);
    hipLaunchKernelGGL(fla_mfma, dim3(NBLK), dim3(512), 0, stream,
                       x, pos, mask, qk_b, v_b, proj_b, vox, ws, outp);
}

// Round 11
// 251.801 us; speedup vs baseline: 2.1010x; 1.7491x over previous
//
#include <hip/hip_runtime.h>

typedef __bf16 bf16x8 __attribute__((ext_vector_type(8)));
typedef float f32x4 __attribute__((ext_vector_type(4)));

#define Bdim 8192
#define NBLK 512
#define NBATCH 16                // 512 blocks x 16 batches
#define Nn 36
#define Cc 128
#define EPSf 1e-4f

// ---- d_ws layout (ushort elements): qk hi/lo split, v/proj single-bf16 ----
#define WS_QK_HI 0
#define WS_QK_LO 32768
#define WS_V_HI  65536
#define WS_P_HI  81920

// ---- LDS arena (bytes); 76288 -> 2 blocks/CU (152576 <= 163840) ----
#define OFF_XH   0        // ush [48][128] swz15  x hi        (stage -> B)
#define OFF_PH   12288    // ush [48][128] swz15  x+pos hi    (stage -> B)
#define OFF_PL   24576    // ush [48][128] swz15  x+pos lo    (stage -> B)
#define OFF_KT   36864    // ush [128 c][52]      raw k3 bf16 (wave-private)
#define OFF_VT   50176    // ush [128 d][52]      v bf16      (wave-private)
#define OFF_QO   63488    // ush [48][128] swz15  q3 then O   (wave-private cols; G reads all)
#define OFF_MASK 75776    // f32 [2][48]  double-buffered
#define OFF_INN  76160    // f32 [2]
#define LDS_BYTES 76288

__device__ inline uint bfh(float f) {
    __bf16 h = (__bf16)f;
    return (uint)(*(const ushort*)&h);
}
__device__ inline uint bfl(float f) {
    float hf = (float)((__bf16)f);
    __bf16 l = (__bf16)(f - hf);
    return (uint)(*(const ushort*)&l);
}
__device__ inline uint pk2h(float a, float b) { return bfh(a) | (bfh(b) << 16); }
__device__ inline uint pk2l(float a, float b) { return bfl(a) | (bfl(b) << 16); }

union U8 { bf16x8 v; uint u[4]; };

// immediate convert+write of one float4 pair into the swizzled staging tiles
__device__ __forceinline__ void put3(char* L, int idx, float4 xv, float4 pv) {
    int n = idx >> 5, c4 = (idx & 31) << 2;
    float s0 = xv.x + pv.x, s1 = xv.y + pv.y;
    float s2 = xv.z + pv.z, s3 = xv.w + pv.w;
    uint ba = (uint)n * 256u + (((uint)(c4 * 2)) ^ (((uint)n & 15u) << 4));
    *(uint2*)(L + OFF_XH + ba) = make_uint2(pk2h(xv.x, xv.y), pk2h(xv.z, xv.w));
    *(uint2*)(L + OFF_PH + ba) = make_uint2(pk2h(s0, s1), pk2h(s2, s3));
    *(uint2*)(L + OFF_PL + ba) = make_uint2(pk2l(s0, s1), pk2l(s2, s3));
}

// straight-line stage of one batch (no state survives this function)
__device__ __forceinline__ void stage_batch(char* L, const float* __restrict__ x,
                                            const float* __restrict__ pos,
                                            const float* __restrict__ mask,
                                            int bb, int t, int wv, int lane, int pe) {
    const float* xg = x + (size_t)bb * (Nn * Cc);
    const float* pg = pos + (size_t)bb * (Nn * Cc);
    {
        int idx = t;
        int n = idx >> 5, c4 = (idx & 31) << 2;
        put3(L, idx, *(const float4*)(xg + n * Cc + c4), *(const float4*)(pg + n * Cc + c4));
    }
    {
        int idx = t + 512;
        int n = idx >> 5, c4 = (idx & 31) << 2;
        put3(L, idx, *(const float4*)(xg + n * Cc + c4), *(const float4*)(pg + n * Cc + c4));
    }
    if (t < 128) {
        int idx = t + 1024;
        int n = idx >> 5, c4 = (idx & 31) << 2;
        put3(L, idx, *(const float4*)(xg + n * Cc + c4), *(const float4*)(pg + n * Cc + c4));
    }
    float mvv = (t < Nn) ? mask[(size_t)bb * Nn + t] : 0.f;
    if (t < 48) ((float*)(L + OFF_MASK))[pe * 48 + t] = mvv;
    if (wv == 0) {
        float s = mvv;                                 // lanes >= 36 hold 0
        s += __shfl_xor(s, 1);  s += __shfl_xor(s, 2);
        s += __shfl_xor(s, 4);  s += __shfl_xor(s, 8);
        s += __shfl_xor(s, 16); s += __shfl_xor(s, 32);
        if (lane == 0) ((float*)(L + OFF_INN))[pe] = 1.f / (s + EPSf);
    }
}

// ---------------- pre-kernel: weights -> frag-ordered bf16 in ws ----------------
__global__ __launch_bounds__(256)
void prep_frags(const float* __restrict__ qk_w, const float* __restrict__ v_w,
                const float* __restrict__ proj_w, ushort* __restrict__ ws)
{
    int e = blockIdx.x * 256 + threadIdx.x;          // 0..65535
    const float* W; int N; int idx; int hi_off; int lo_off;
    if (e < 32768)      { W = qk_w;   N = 256; hi_off = WS_QK_HI; lo_off = WS_QK_LO; idx = e; }
    else if (e < 49152) { W = v_w;    N = 128; hi_off = WS_V_HI;  lo_off = -1;       idx = e - 32768; }
    else                { W = proj_w; N = 128; hi_off = WS_P_HI;  lo_off = -1;       idx = e - 49152; }
    int j    = idx & 7;
    int lane = (idx >> 3) & 63;
    int ks   = (idx >> 9) & 3;
    int ct   = idx >> 11;
    int col  = ct * 16 + (lane & 15);
    int k    = ks * 32 + (lane >> 4) * 8 + j;
    float v  = W[k * N + col];
    ws[hi_off + idx] = (ushort)bfh(v);
    if (lo_off >= 0) ws[lo_off + idx] = (ushort)bfl(v);
}

// -------- main: 512 thr = 8 waves; wave h owns head h; 2 barriers per batch --------
__global__ __launch_bounds__(512, 2)
void fla_mfma(const float* __restrict__ x, const float* __restrict__ pos,
              const float* __restrict__ mask, const float* __restrict__ qk_b,
              const float* __restrict__ v_b, const float* __restrict__ proj_b,
              const int* __restrict__ vox, const ushort* __restrict__ ws,
              float* __restrict__ out)
{
    __shared__ __align__(16) char lds[LDS_BYTES];
    const int t = threadIdx.x;
    const int lane = t & 63;
    const int wv = t >> 6;                           // wave = head
    const int  rsel = lane & 15;
    const int  grp  = lane >> 4;
    const uint kgrp = (uint)grp * 8u;
    const uint sw   = ((uint)rsel) << 4;             // row&15 swizzle on frag reads
    const int base = blockIdx.x * NBATCH;

    // hoisted per-lane constants
    const int   c16 = wv * 16 + rsel;
    const float qb = qk_b[c16];
    const float kb = qk_b[Cc + c16];
    const float vb = v_b[c16];
    const float pb = proj_b[c16];

    // prologue: stage batch 0 (buffers pe=0)
    stage_batch(lds, x, pos, mask, base, t, wv, lane, 0);
    __syncthreads();

    #pragma unroll 1
    for (int i = 0; i < NBATCH; ++i) {
        const int pe = i & 1;

        // ---------------- B_qk: q,k column-tiles of head wv (split-bf16) ------------
        f32x4 accQ[3], accK[3];
        #pragma unroll
        for (int rt = 0; rt < 3; ++rt) {
            accQ[rt] = (f32x4){0.f, 0.f, 0.f, 0.f};
            accK[rt] = (f32x4){0.f, 0.f, 0.f, 0.f};
        }
        #pragma unroll
        for (int ks = 0; ks < 4; ++ks) {
            uint ka = (((uint)(ks * 32) + kgrp) * 2u) ^ sw;
            bf16x8 ph[3], pl[3];
            #pragma unroll
            for (int rt = 0; rt < 3; ++rt) {
                uint ba = (uint)(rt * 16 + rsel) * 256u + ka;
                ph[rt] = *(const bf16x8*)(lds + OFF_PH + ba);
                pl[rt] = *(const bf16x8*)(lds + OFF_PL + ba);
            }
            int fq = ((wv * 4 + ks) * 64 + lane) * 8;
            int fk = (((8 + wv) * 4 + ks) * 64 + lane) * 8;
            bf16x8 bqh = *(const bf16x8*)(ws + WS_QK_HI + fq);
            bf16x8 bql = *(const bf16x8*)(ws + WS_QK_LO + fq);
            bf16x8 bkh = *(const bf16x8*)(ws + WS_QK_HI + fk);
            bf16x8 bkl = *(const bf16x8*)(ws + WS_QK_LO + fk);
            #pragma unroll
            for (int rt = 0; rt < 3; ++rt) {
                accQ[rt] = __builtin_amdgcn_mfma_f32_16x16x32_bf16(ph[rt], bqh, accQ[rt], 0, 0, 0);
                accQ[rt] = __builtin_amdgcn_mfma_f32_16x16x32_bf16(ph[rt], bql, accQ[rt], 0, 0, 0);
                accQ[rt] = __builtin_amdgcn_mfma_f32_16x16x32_bf16(pl[rt], bqh, accQ[rt], 0, 0, 0);
                accK[rt] = __builtin_amdgcn_mfma_f32_16x16x32_bf16(ph[rt], bkh, accK[rt], 0, 0, 0);
                accK[rt] = __builtin_amdgcn_mfma_f32_16x16x32_bf16(ph[rt], bkl, accK[rt], 0, 0, 0);
                accK[rt] = __builtin_amdgcn_mfma_f32_16x16x32_bf16(pl[rt], bkh, accK[rt], 0, 0, 0);
            }
        }
        // ---------------- B_v: v column-tile of head wv (single-bf16) ---------------
        f32x4 accV[3];
        #pragma unroll
        for (int rt = 0; rt < 3; ++rt) accV[rt] = (f32x4){0.f, 0.f, 0.f, 0.f};
        #pragma unroll
        for (int ks = 0; ks < 4; ++ks) {
            uint ka = (((uint)(ks * 32) + kgrp) * 2u) ^ sw;
            bf16x8 xh[3];
            #pragma unroll
            for (int rt = 0; rt < 3; ++rt)
                xh[rt] = *(const bf16x8*)(lds + OFF_XH + (uint)(rt * 16 + rsel) * 256u + ka);
            int fv = ((wv * 4 + ks) * 64 + lane) * 8;
            bf16x8 bvh = *(const bf16x8*)(ws + WS_V_HI + fv);
            #pragma unroll
            for (int rt = 0; rt < 3; ++rt)
                accV[rt] = __builtin_amdgcn_mfma_f32_16x16x32_bf16(xh[rt], bvh, accV[rt], 0, 0, 0);
        }
        __syncthreads();                 // barrier A: staging consumed, may overwrite

        // ---------------- C_qk: q3 -> QO (own cols), raw k3 -> KT (own cols) --------
        {
            const float* sM = (const float*)(lds + OFF_MASK) + pe * 48;
            uint cb2 = (uint)(c16 * 2);
            #pragma unroll
            for (int rt = 0; rt < 3; ++rt) {
                #pragma unroll
                for (int r = 0; r < 4; ++r) {
                    int row = rt * 16 + grp * 4 + r;
                    if (row < Nn) {
                        float q1 = accQ[rt][r] + qb;
                        float q3 = q1 * q1 * q1;
                        uint ba = (uint)row * 256u + (cb2 ^ (((uint)row & 15u) << 4));
                        *(ushort*)(lds + OFF_QO + ba) = (ushort)bfh(q3);
                    }
                }
            }
            #pragma unroll
            for (int rt = 0; rt < 3; ++rt) {
                float k3v[4];
                #pragma unroll
                for (int r = 0; r < 4; ++r) {
                    int row = rt * 16 + grp * 4 + r;
                    float k1 = (accK[rt][r] + kb) * sM[row];
                    float k3 = k1 * k1 * k1;
                    k3v[r] = (rt == 2 && grp != 0) ? 0.f : k3;    // pad rows exact 0
                }
                uint addr = OFF_KT + (uint)(c16 * 52 + rt * 16 + grp * 4) * 2u;
                *(uint2*)(lds + addr) = make_uint2(pk2h(k3v[0], k3v[1]), pk2h(k3v[2], k3v[3]));
            }
        }
        // ---------------- C_v: v(+bias) -> VT (own cols) ----------------------------
        #pragma unroll
        for (int rt = 0; rt < 3; ++rt) {
            float a0 = accV[rt][0] + vb, a1 = accV[rt][1] + vb;
            float a2 = accV[rt][2] + vb, a3 = accV[rt][3] + vb;
            if (rt == 2 && grp != 0) { a0 = 0.f; a1 = 0.f; a2 = 0.f; a3 = 0.f; }
            uint addr = OFF_VT + (uint)(c16 * 52 + rt * 16 + grp * 4) * 2u;
            *(uint2*)(lds + addr) = make_uint2(pk2h(a0, a1), pk2h(a2, a3));
        }

        // ---------------- PA: stage batch i+1 (immediate, no held regs) -------------
        if (i + 1 < NBATCH)
            stage_batch(lds, x, pos, mask, base + i + 1, t, wv, lane, pe ^ 1);

        // ---------------- D: kv-hat = invkn[c]*(k3^T @ v), wave-private -------------
        f32x4 kvacc;
        {
            uint a0 = OFF_KT + (uint)(c16 * 52 + grp * 8) * 2u;
            uint b0 = OFF_VT + (uint)(c16 * 52 + grp * 8) * 2u;
            bf16x8 kA0 = *(const bf16x8*)(lds + a0);
            bf16x8 vB0 = *(const bf16x8*)(lds + b0);
            U8 kA1, vB1;
            kA1.u[0] = kA1.u[1] = kA1.u[2] = kA1.u[3] = 0u;
            vB1.u[0] = vB1.u[1] = vB1.u[2] = vB1.u[3] = 0u;
            if (grp < 2) {                               // n = 32 + grp*8 .. +7
                kA1.v = *(const bf16x8*)(lds + a0 + 64);
                vB1.v = *(const bf16x8*)(lds + b0 + 64);
            }
            float s = 0.f;
            #pragma unroll
            for (int j = 0; j < 8; ++j) { float q = (float)kA0[j]; s += q * q; }
            #pragma unroll
            for (int j = 0; j < 8; ++j) { float q = (float)kA1.v[j]; s += q * q; }
            s += __shfl_xor(s, 16);
            s += __shfl_xor(s, 32);
            float invkn = 1.f / (EPSf + sqrtf(s));

            kvacc = (f32x4){0.f, 0.f, 0.f, 0.f};
            kvacc = __builtin_amdgcn_mfma_f32_16x16x32_bf16(kA0, vB0, kvacc, 0, 0, 0);
            kvacc = __builtin_amdgcn_mfma_f32_16x16x32_bf16(kA1.v, vB1.v, kvacc, 0, 0, 0);
            #pragma unroll
            for (int r = 0; r < 4; ++r)
                kvacc[r] *= __shfl(invkn, grp * 4 + r);
        }

        // ---------------- E: out = invn[row]*inn * (q3 @ kv-hat) -> O (own cols) ----
        {
            float bv[8];
            #pragma unroll
            for (int j = 0; j < 8; ++j)
                bv[j] = __shfl(kvacc[j & 3], rsel + 16 * (2 * grp + (j >> 2)));
            if (grp >= 2) {
                #pragma unroll
                for (int j = 0; j < 8; ++j) bv[j] = 0.f;
            }
            U8 bkv;
            bkv.u[0] = pk2h(bv[0], bv[1]); bkv.u[1] = pk2h(bv[2], bv[3]);
            bkv.u[2] = pk2h(bv[4], bv[5]); bkv.u[3] = pk2h(bv[6], bv[7]);

            float inn = ((const float*)(lds + OFF_INN))[pe];
            U8 aq[3];
            #pragma unroll
            for (int rt = 0; rt < 3; ++rt) {
                int row = rt * 16 + rsel;
                aq[rt].u[0] = aq[rt].u[1] = aq[rt].u[2] = aq[rt].u[3] = 0u;
                if (grp < 2 && row < Nn)
                    aq[rt].v = *(const bf16x8*)(lds + OFF_QO + (uint)row * 256u +
                                                (((uint)(wv * 32 + grp * 16)) ^ sw));
            }
            f32x4 oacc[3];
            float invn[3];
            #pragma unroll
            for (int rt = 0; rt < 3; ++rt) {
                float s = 0.f;
                #pragma unroll
                for (int j = 0; j < 8; ++j) { float q = (float)aq[rt].v[j]; s += q * q; }
                s += __shfl_xor(s, 16);                  // lanes 0..15 hold full sum
                invn[rt] = 1.f / (EPSf + sqrtf(s));
                f32x4 o = (f32x4){0.f, 0.f, 0.f, 0.f};
                o = __builtin_amdgcn_mfma_f32_16x16x32_bf16(aq[rt].v, bkv.v, o, 0, 0, 0);
                oacc[rt] = o;
            }
            uint cb2 = (uint)(c16 * 2);
            #pragma unroll
            for (int rt = 0; rt < 3; ++rt) {
                #pragma unroll
                for (int r = 0; r < 4; ++r) {
                    int rr = grp * 4 + r;
                    int row = rt * 16 + rr;
                    if (row < Nn) {
                        float fac = __shfl(invn[rt], rr) * inn;
                        float val = oacc[rt][r] * fac;
                        uint ba = (uint)row * 256u + (cb2 ^ (((uint)row & 15u) << 4));
                        *(ushort*)(lds + OFF_QO + ba) = (ushort)bfh(val);
                    }
                }
            }
        }
        __syncthreads();                 // barrier B: O complete; staging(i+1) ready

        // ---------------- G: proj GEMM (own out-cols, reads all O) + scatter --------
        {
            f32x4 accP[3];
            #pragma unroll
            for (int rt = 0; rt < 3; ++rt) accP[rt] = (f32x4){0.f, 0.f, 0.f, 0.f};
            #pragma unroll
            for (int ks = 0; ks < 4; ++ks) {
                uint ka = (((uint)(ks * 32) + kgrp) * 2u) ^ sw;
                bf16x8 oa[3];
                #pragma unroll
                for (int rt = 0; rt < 3; ++rt)
                    oa[rt] = *(const bf16x8*)(lds + OFF_QO + (uint)(rt * 16 + rsel) * 256u + ka);
                int fp = ((wv * 4 + ks) * 64 + lane) * 8;
                bf16x8 bp = *(const bf16x8*)(ws + WS_P_HI + fp);
                #pragma unroll
                for (int rt = 0; rt < 3; ++rt)
                    accP[rt] = __builtin_amdgcn_mfma_f32_16x16x32_bf16(oa[rt], bp, accP[rt], 0, 0, 0);
            }
            const int* voxb = vox + (size_t)(base + i) * Nn;
            #pragma unroll
            for (int rt = 0; rt < 3; ++rt) {
                #pragma unroll
                for (int r = 0; r < 4; ++r) {
                    int row = rt * 16 + grp * 4 + r;
                    if (row < Nn)
                        out[(size_t)voxb[row] * Cc + c16] = accP[rt][r] + pb;
                }
            }
        }
        // next iteration's barrier A protects QO (G reads) from C_qk(i+1) writes
    }
}

extern "C" void kernel_launch(void* const* d_in, const int* in_sizes, int n_in,
                              void* d_out, int out_size, void* d_ws, size_t ws_size,
                              hipStream_t stream) {
    (void)in_sizes; (void)n_in; (void)out_size; (void)ws_size;
    const float* x      = (const float*)d_in[0];
    const float* pos    = (const float*)d_in[1];
    const float* mask   = (const float*)d_in[2];
    const float* qk_w   = (const float*)d_in[3];
    const float* qk_b   = (const float*)d_in[4];
    const float* v_w    = (const float*)d_in[5];
    const float* v_b    = (const float*)d_in[6];
    const float* proj_w = (const float*)d_in[7];
    const float* proj_b = (const float*)d_in[8];
    // d_in[9] = coords (unused)
    const int*   vox    = (const int*)d_in[10];
    ushort* ws = (ushort*)d_ws;            // 192 KiB scratch used
    float* outp = (float*)d_out;

    hipLaunchKernelGGL(prep_frags, dim3(256), dim3(256), 0, stream, qk_w, v_w, proj_w, ws);
    hipLaunchKernelGGL(fla_mfma, dim3(NBLK), dim3(512), 0, stream,
                       x, pos, mask, qk_b, v_b, proj_b, vox, ws, outp);
}

// Round 12
// 228.609 us; speedup vs baseline: 2.3141x; 1.1015x over previous
//
#include <hip/hip_runtime.h>

typedef __bf16 bf16x8 __attribute__((ext_vector_type(8)));
typedef float f32x4 __attribute__((ext_vector_type(4)));

#define Bdim 8192
#define NBLK 512
#define NBATCH 16                // 512 blocks x 16 batches
#define Nn 36
#define Cc 128
#define EPSf 1e-4f

// ---- d_ws layout (ushort elements): qk hi/lo split, v/proj single-bf16 ----
#define WS_QK_HI 0
#define WS_QK_LO 32768
#define WS_V_HI  65536
#define WS_P_HI  81920

// ---- per-batch LDS arena (bytes); 2 arenas = 151968 -> 1 block/CU (by design) ----
#define OFF_XH   0        // ush [48][128] swz15  x hi        (S -> B)
#define OFF_PH   12288    // ush [48][128] swz15  x+pos hi    (S -> B)
#define OFF_PL   24576    // ush [48][128] swz15  x+pos lo    (S -> B)
#define OFF_KT   36864    // ush [128 c][52]      raw k3 bf16 (wave-private, C->DE)
#define OFF_VT   50176    // ush [128 d][52]      v bf16      (wave-private, C->DE)
#define OFF_QO   63488    // ush [48][128] swz15  q3 then O   (C/DE own cols; G all)
#define OFF_MASK 75776    // f32 [48]
#define OFF_INN  75968    // f32
#define AST      75984    // 16-aligned arena stride

__device__ inline uint bfh(float f) {
    __bf16 h = (__bf16)f;
    return (uint)(*(const ushort*)&h);
}
__device__ inline uint bfl(float f) {
    float hf = (float)((__bf16)f);
    __bf16 l = (__bf16)(f - hf);
    return (uint)(*(const ushort*)&l);
}
__device__ inline uint pk2h(float a, float b) { return bfh(a) | (bfh(b) << 16); }
__device__ inline uint pk2l(float a, float b) { return bfl(a) | (bfl(b) << 16); }

union U8 { bf16x8 v; uint u[4]; };

// immediate convert+write of one float4 pair into the swizzled staging tiles
__device__ __forceinline__ void put3(char* L, int idx, float4 xv, float4 pv) {
    int n = idx >> 5, c4 = (idx & 31) << 2;
    float s0 = xv.x + pv.x, s1 = xv.y + pv.y;
    float s2 = xv.z + pv.z, s3 = xv.w + pv.w;
    uint ba = (uint)n * 256u + (((uint)(c4 * 2)) ^ (((uint)n & 15u) << 4));
    *(uint2*)(L + OFF_XH + ba) = make_uint2(pk2h(xv.x, xv.y), pk2h(xv.z, xv.w));
    *(uint2*)(L + OFF_PH + ba) = make_uint2(pk2h(s0, s1), pk2h(s2, s3));
    *(uint2*)(L + OFF_PL + ba) = make_uint2(pk2l(s0, s1), pk2l(s2, s3));
}

// ---------------- pre-kernel: weights -> frag-ordered bf16 in ws ----------------
__global__ __launch_bounds__(256)
void prep_frags(const float* __restrict__ qk_w, const float* __restrict__ v_w,
                const float* __restrict__ proj_w, ushort* __restrict__ ws)
{
    int e = blockIdx.x * 256 + threadIdx.x;          // 0..65535
    const float* W; int N; int idx; int hi_off; int lo_off;
    if (e < 32768)      { W = qk_w;   N = 256; hi_off = WS_QK_HI; lo_off = WS_QK_LO; idx = e; }
    else if (e < 49152) { W = v_w;    N = 128; hi_off = WS_V_HI;  lo_off = -1;       idx = e - 32768; }
    else                { W = proj_w; N = 128; hi_off = WS_P_HI;  lo_off = -1;       idx = e - 49152; }
    int j    = idx & 7;
    int lane = (idx >> 3) & 63;
    int ks   = (idx >> 9) & 3;
    int ct   = idx >> 11;
    int col  = ct * 16 + (lane & 15);
    int k    = ks * 32 + (lane >> 4) * 8 + j;
    float v  = W[k * N + col];
    ws[hi_off + idx] = (ushort)bfh(v);
    if (lo_off >= 0) ws[lo_off + idx] = (ushort)bfl(v);
}

// ---- main: 8 waves, wave h owns head h; double-buffered arenas; 1 barrier/batch ----
__global__ __launch_bounds__(512, 2)
void fla_mfma(const float* __restrict__ x, const float* __restrict__ pos,
              const float* __restrict__ mask, const float* __restrict__ qk_b,
              const float* __restrict__ v_b, const float* __restrict__ proj_b,
              const int* __restrict__ vox, const ushort* __restrict__ ws,
              float* __restrict__ out)
{
    __shared__ __align__(16) char lds[2][AST];
    const int t = threadIdx.x;
    const int lane = t & 63;
    const int wv = t >> 6;                           // wave = head
    const int  rsel = lane & 15;
    const int  grp  = lane >> 4;
    const uint kgrp = (uint)grp * 8u;
    const uint sw   = ((uint)rsel) << 4;             // row&15 swizzle on frag reads
    const int base = blockIdx.x * NBATCH;

    const int   c16 = wv * 16 + rsel;
    const float qb = qk_b[c16];
    const float kb = qk_b[Cc + c16];
    const float vb = v_b[c16];
    const float pb = proj_b[c16];

    // persistent qk B-fragments (64 VGPRs, loaded once)
    bf16x8 BQH[4], BQL[4], BKH[4], BKL[4];
    #pragma unroll
    for (int ks = 0; ks < 4; ++ks) {
        int fq = ((wv * 4 + ks) * 64 + lane) * 8;
        int fk = (((8 + wv) * 4 + ks) * 64 + lane) * 8;
        BQH[ks] = *(const bf16x8*)(ws + WS_QK_HI + fq);
        BQL[ks] = *(const bf16x8*)(ws + WS_QK_LO + fq);
        BKH[ks] = *(const bf16x8*)(ws + WS_QK_HI + fk);
        BKL[ks] = *(const bf16x8*)(ws + WS_QK_LO + fk);
    }

    // zero pad rows 36..47 of XH/PH/PL/QO in both arenas (stay zero forever)
    #pragma unroll
    for (int z0 = 0; z0 < 3; ++z0) {
        int z = t + z0 * 512;                        // 0..1535 = 2 arenas x 4 regions x 192 uint4
        int ar = z >= 768;
        int zz = z & 767;
        int reg = zz / 192;
        int off = (zz % 192) * 16;
        uint ro = (reg == 0) ? OFF_XH : (reg == 1) ? OFF_PH : (reg == 2) ? OFF_PL : OFF_QO;
        *(uint4*)(lds[ar] + ro + 36 * 256 + off) = make_uint4(0u, 0u, 0u, 0u);
    }

    // prologue: stage batch 0 into arena 0 (straight-line)
    {
        const float* xg = x + (size_t)base * (Nn * Cc);
        const float* pg = pos + (size_t)base * (Nn * Cc);
        { int n = t >> 5, c4 = (t & 31) << 2;
          put3(lds[0], t, *(const float4*)(xg + n * Cc + c4), *(const float4*)(pg + n * Cc + c4)); }
        { int idx = t + 512; int n = idx >> 5, c4 = (idx & 31) << 2;
          put3(lds[0], idx, *(const float4*)(xg + n * Cc + c4), *(const float4*)(pg + n * Cc + c4)); }
        if (t < 128) { int idx = t + 1024; int n = idx >> 5, c4 = (idx & 31) << 2;
          put3(lds[0], idx, *(const float4*)(xg + n * Cc + c4), *(const float4*)(pg + n * Cc + c4)); }
        float mvv = (t < Nn) ? mask[(size_t)base * Nn + t] : 0.f;
        if (t < 48) ((float*)(lds[0] + OFF_MASK))[t] = mvv;
        if (wv == 0) {
            float s = mvv;
            s += __shfl_xor(s, 1);  s += __shfl_xor(s, 2);
            s += __shfl_xor(s, 4);  s += __shfl_xor(s, 8);
            s += __shfl_xor(s, 16); s += __shfl_xor(s, 32);
            if (lane == 0) *(float*)(lds[0] + OFF_INN) = 1.f / (s + EPSf);
        }
    }
    __syncthreads();

    #pragma unroll 1
    for (int i = 0; i < NBATCH; ++i) {
        char* L  = lds[i & 1];
        char* Ln = lds[(i + 1) & 1];
        const bool more = (i + 1 < NBATCH);

        // -------- S_load(i+1): issue global loads early (T14 issue-early) -----------
        float4 lx0, lp0, lx1, lp1, lx2, lp2;
        float lmv = 0.f;
        if (more) {
            const float* xg = x + (size_t)(base + i + 1) * (Nn * Cc);
            const float* pg = pos + (size_t)(base + i + 1) * (Nn * Cc);
            { int n = t >> 5, c4 = (t & 31) << 2;
              lx0 = *(const float4*)(xg + n * Cc + c4);
              lp0 = *(const float4*)(pg + n * Cc + c4); }
            { int idx = t + 512; int n = idx >> 5, c4 = (idx & 31) << 2;
              lx1 = *(const float4*)(xg + n * Cc + c4);
              lp1 = *(const float4*)(pg + n * Cc + c4); }
            if (t < 128) { int idx = t + 1024; int n = idx >> 5, c4 = (idx & 31) << 2;
              lx2 = *(const float4*)(xg + n * Cc + c4);
              lp2 = *(const float4*)(pg + n * Cc + c4); }
            lmv = (t < Nn) ? mask[(size_t)(base + i + 1) * Nn + t] : 0.f;
        }
        __builtin_amdgcn_sched_barrier(0);           // pin: loads issue before compute

        // -------- B_qk: q,k column-tiles of head wv (split-bf16, pinned B-frags) ----
        f32x4 accQ[3], accK[3];
        #pragma unroll
        for (int rt = 0; rt < 3; ++rt) {
            accQ[rt] = (f32x4){0.f, 0.f, 0.f, 0.f};
            accK[rt] = (f32x4){0.f, 0.f, 0.f, 0.f};
        }
        #pragma unroll
        for (int ks = 0; ks < 4; ++ks) {
            uint ka = (((uint)(ks * 32) + kgrp) * 2u) ^ sw;
            bf16x8 ph[3], pl[3];
            #pragma unroll
            for (int rt = 0; rt < 3; ++rt) {
                uint ba = (uint)(rt * 16 + rsel) * 256u + ka;
                ph[rt] = *(const bf16x8*)(L + OFF_PH + ba);
                pl[rt] = *(const bf16x8*)(L + OFF_PL + ba);
            }
            #pragma unroll
            for (int rt = 0; rt < 3; ++rt) {
                accQ[rt] = __builtin_amdgcn_mfma_f32_16x16x32_bf16(ph[rt], BQH[ks], accQ[rt], 0, 0, 0);
                accQ[rt] = __builtin_amdgcn_mfma_f32_16x16x32_bf16(ph[rt], BQL[ks], accQ[rt], 0, 0, 0);
                accQ[rt] = __builtin_amdgcn_mfma_f32_16x16x32_bf16(pl[rt], BQH[ks], accQ[rt], 0, 0, 0);
                accK[rt] = __builtin_amdgcn_mfma_f32_16x16x32_bf16(ph[rt], BKH[ks], accK[rt], 0, 0, 0);
                accK[rt] = __builtin_amdgcn_mfma_f32_16x16x32_bf16(ph[rt], BKL[ks], accK[rt], 0, 0, 0);
                accK[rt] = __builtin_amdgcn_mfma_f32_16x16x32_bf16(pl[rt], BKH[ks], accK[rt], 0, 0, 0);
            }
        }
        // -------- B_v: v column-tile of head wv (single-bf16) -----------------------
        f32x4 accV[3];
        #pragma unroll
        for (int rt = 0; rt < 3; ++rt) accV[rt] = (f32x4){0.f, 0.f, 0.f, 0.f};
        #pragma unroll
        for (int ks = 0; ks < 4; ++ks) {
            uint ka = (((uint)(ks * 32) + kgrp) * 2u) ^ sw;
            bf16x8 xh[3];
            #pragma unroll
            for (int rt = 0; rt < 3; ++rt)
                xh[rt] = *(const bf16x8*)(L + OFF_XH + (uint)(rt * 16 + rsel) * 256u + ka);
            int fv = ((wv * 4 + ks) * 64 + lane) * 8;
            bf16x8 bvh = *(const bf16x8*)(ws + WS_V_HI + fv);
            #pragma unroll
            for (int rt = 0; rt < 3; ++rt)
                accV[rt] = __builtin_amdgcn_mfma_f32_16x16x32_bf16(xh[rt], bvh, accV[rt], 0, 0, 0);
        }

        // -------- C_qk: q3 -> QO (own cols), raw k3 -> KT (own cols) ----------------
        {
            const float* sM = (const float*)(L + OFF_MASK);
            uint cb2 = (uint)(c16 * 2);
            #pragma unroll
            for (int rt = 0; rt < 3; ++rt) {
                #pragma unroll
                for (int r = 0; r < 4; ++r) {
                    int row = rt * 16 + grp * 4 + r;
                    if (row < Nn) {
                        float q1 = accQ[rt][r] + qb;
                        float q3 = q1 * q1 * q1;
                        uint ba = (uint)row * 256u + (cb2 ^ (((uint)row & 15u) << 4));
                        *(ushort*)(L + OFF_QO + ba) = (ushort)bfh(q3);
                    }
                }
            }
            #pragma unroll
            for (int rt = 0; rt < 3; ++rt) {
                float k3v[4];
                #pragma unroll
                for (int r = 0; r < 4; ++r) {
                    int row = rt * 16 + grp * 4 + r;
                    float k1 = (accK[rt][r] + kb) * sM[row];
                    float k3 = k1 * k1 * k1;
                    k3v[r] = (rt == 2 && grp != 0) ? 0.f : k3;    // pad rows exact 0
                }
                uint addr = OFF_KT + (uint)(c16 * 52 + rt * 16 + grp * 4) * 2u;
                *(uint2*)(L + addr) = make_uint2(pk2h(k3v[0], k3v[1]), pk2h(k3v[2], k3v[3]));
            }
        }
        // -------- C_v: v(+bias) -> VT (own cols) ------------------------------------
        #pragma unroll
        for (int rt = 0; rt < 3; ++rt) {
            float a0 = accV[rt][0] + vb, a1 = accV[rt][1] + vb;
            float a2 = accV[rt][2] + vb, a3 = accV[rt][3] + vb;
            if (rt == 2 && grp != 0) { a0 = 0.f; a1 = 0.f; a2 = 0.f; a3 = 0.f; }
            uint addr = OFF_VT + (uint)(c16 * 52 + rt * 16 + grp * 4) * 2u;
            *(uint2*)(L + addr) = make_uint2(pk2h(a0, a1), pk2h(a2, a3));
        }

        // -------- D: kv-hat = invkn[c]*(k3^T @ v), wave-private ---------------------
        f32x4 kvacc;
        {
            uint a0 = OFF_KT + (uint)(c16 * 52 + grp * 8) * 2u;
            uint b0 = OFF_VT + (uint)(c16 * 52 + grp * 8) * 2u;
            bf16x8 kA0 = *(const bf16x8*)(L + a0);
            bf16x8 vB0 = *(const bf16x8*)(L + b0);
            U8 kA1, vB1;
            kA1.u[0] = kA1.u[1] = kA1.u[2] = kA1.u[3] = 0u;
            vB1.u[0] = vB1.u[1] = vB1.u[2] = vB1.u[3] = 0u;
            if (grp < 2) {                               // n = 32 + grp*8 .. +7
                kA1.v = *(const bf16x8*)(L + a0 + 64);
                vB1.v = *(const bf16x8*)(L + b0 + 64);
            }
            float s = 0.f;
            #pragma unroll
            for (int j = 0; j < 8; ++j) { float q = (float)kA0[j]; s += q * q; }
            #pragma unroll
            for (int j = 0; j < 8; ++j) { float q = (float)kA1.v[j]; s += q * q; }
            s += __shfl_xor(s, 16);
            s += __shfl_xor(s, 32);
            float invkn = 1.f / (EPSf + sqrtf(s));

            kvacc = (f32x4){0.f, 0.f, 0.f, 0.f};
            kvacc = __builtin_amdgcn_mfma_f32_16x16x32_bf16(kA0, vB0, kvacc, 0, 0, 0);
            kvacc = __builtin_amdgcn_mfma_f32_16x16x32_bf16(kA1.v, vB1.v, kvacc, 0, 0, 0);
            #pragma unroll
            for (int r = 0; r < 4; ++r)
                kvacc[r] *= __shfl(invkn, grp * 4 + r);
        }

        // -------- E: out = invn[row]*inn * (q3 @ kv-hat) -> O (own cols) ------------
        {
            float bv[8];
            #pragma unroll
            for (int j = 0; j < 8; ++j)
                bv[j] = __shfl(kvacc[j & 3], rsel + 16 * (2 * grp + (j >> 2)));
            if (grp >= 2) {
                #pragma unroll
                for (int j = 0; j < 8; ++j) bv[j] = 0.f;
            }
            U8 bkv;
            bkv.u[0] = pk2h(bv[0], bv[1]); bkv.u[1] = pk2h(bv[2], bv[3]);
            bkv.u[2] = pk2h(bv[4], bv[5]); bkv.u[3] = pk2h(bv[6], bv[7]);

            float inn = *(const float*)(L + OFF_INN);
            U8 aq[3];
            #pragma unroll
            for (int rt = 0; rt < 3; ++rt) {
                int row = rt * 16 + rsel;
                aq[rt].u[0] = aq[rt].u[1] = aq[rt].u[2] = aq[rt].u[3] = 0u;
                if (grp < 2 && row < Nn)
                    aq[rt].v = *(const bf16x8*)(L + OFF_QO + (uint)row * 256u +
                                                (((uint)(wv * 32 + grp * 16)) ^ sw));
            }
            f32x4 oacc[3];
            float invn[3];
            #pragma unroll
            for (int rt = 0; rt < 3; ++rt) {
                float s = 0.f;
                #pragma unroll
                for (int j = 0; j < 8; ++j) { float q = (float)aq[rt].v[j]; s += q * q; }
                s += __shfl_xor(s, 16);                  // lanes 0..15 hold full sum
                invn[rt] = 1.f / (EPSf + sqrtf(s));
                f32x4 o = (f32x4){0.f, 0.f, 0.f, 0.f};
                o = __builtin_amdgcn_mfma_f32_16x16x32_bf16(aq[rt].v, bkv.v, o, 0, 0, 0);
                oacc[rt] = o;
            }
            uint cb2 = (uint)(c16 * 2);
            #pragma unroll
            for (int rt = 0; rt < 3; ++rt) {
                #pragma unroll
                for (int r = 0; r < 4; ++r) {
                    int rr = grp * 4 + r;
                    int row = rt * 16 + rr;
                    if (row < Nn) {
                        float fac = __shfl(invn[rt], rr) * inn;
                        float val = oacc[rt][r] * fac;
                        uint ba = (uint)row * 256u + (cb2 ^ (((uint)row & 15u) << 4));
                        *(ushort*)(L + OFF_QO + ba) = (ushort)bfh(val);
                    }
                }
            }
        }

        // -------- S_write(i+1) -> Ln (T14 write-late; stalls on vmcnt here) ---------
        if (more) {
            put3(Ln, t, lx0, lp0);
            put3(Ln, t + 512, lx1, lp1);
            if (t < 128) put3(Ln, t + 1024, lx2, lp2);
            if (t < 48) ((float*)(Ln + OFF_MASK))[t] = lmv;
            if (wv == 0) {
                float s = lmv;
                s += __shfl_xor(s, 1);  s += __shfl_xor(s, 2);
                s += __shfl_xor(s, 4);  s += __shfl_xor(s, 8);
                s += __shfl_xor(s, 16); s += __shfl_xor(s, 32);
                if (lane == 0) *(float*)(Ln + OFF_INN) = 1.f / (s + EPSf);
            }
        }
        __syncthreads();      // THE barrier: O(a) done; staging(a') done

        // -------- G: proj GEMM (own out-cols, reads all O) + scatter ----------------
        {
            f32x4 accP[3];
            #pragma unroll
            for (int rt = 0; rt < 3; ++rt) accP[rt] = (f32x4){0.f, 0.f, 0.f, 0.f};
            #pragma unroll
            for (int ks = 0; ks < 4; ++ks) {
                uint ka = (((uint)(ks * 32) + kgrp) * 2u) ^ sw;
                bf16x8 oa[3];
                #pragma unroll
                for (int rt = 0; rt < 3; ++rt)
                    oa[rt] = *(const bf16x8*)(L + OFF_QO + (uint)(rt * 16 + rsel) * 256u + ka);
                int fp = ((wv * 4 + ks) * 64 + lane) * 8;
                bf16x8 bp = *(const bf16x8*)(ws + WS_P_HI + fp);
                #pragma unroll
                for (int rt = 0; rt < 3; ++rt)
                    accP[rt] = __builtin_amdgcn_mfma_f32_16x16x32_bf16(oa[rt], bp, accP[rt], 0, 0, 0);
            }
            const int* voxb = vox + (size_t)(base + i) * Nn;
            #pragma unroll
            for (int rt = 0; rt < 3; ++rt) {
                #pragma unroll
                for (int r = 0; r < 4; ++r) {
                    int row = rt * 16 + grp * 4 + r;
                    if (row < Nn)
                        out[(size_t)voxb[row] * Cc + c16] = accP[rt][r] + pb;
                }
            }
        }
        // next span's C(i+1) writes the OTHER arena's QO; G(i) reads are safe.
    }
}

extern "C" void kernel_launch(void* const* d_in, const int* in_sizes, int n_in,
                              void* d_out, int out_size, void* d_ws, size_t ws_size,
                              hipStream_t stream) {
    (void)in_sizes; (void)n_in; (void)out_size; (void)ws_size;
    const float* x      = (const float*)d_in[0];
    const float* pos    = (const float*)d_in[1];
    const float* mask   = (const float*)d_in[2];
    const float* qk_w   = (const float*)d_in[3];
    const float* qk_b   = (const float*)d_in[4];
    const float* v_w    = (const float*)d_in[5];
    const float* v_b    = (const float*)d_in[6];
    const float* proj_w = (const float*)d_in[7];
    const float* proj_b = (const float*)d_in[8];
    // d_in[9] = coords (unused)
    const int*   vox    = (const int*)d_in[10];
    ushort* ws = (ushort*)d_ws;            // 192 KiB scratch used
    float* outp = (float*)d_out;

    hipLaunchKernelGGL(prep_frags, dim3(256), dim3(256), 0, stream, qk_w, v_w, proj_w, ws);
    hipLaunchKernelGGL(fla_mfma, dim3(NBLK), dim3(512), 0, stream,
                       x, pos, mask, qk_b, v_b, proj_b, vox, ws, outp);
}

// Round 13
// 224.498 us; speedup vs baseline: 2.3565x; 1.0183x over previous
//
#include <hip/hip_runtime.h>

typedef __bf16 bf16x8 __attribute__((ext_vector_type(8)));
typedef float f32x4 __attribute__((ext_vector_type(4)));

#define Bdim 8192
#define Nn 36
#define Cc 128
#define EPSf 1e-4f

// ---- d_ws layout (ushort elements): qk hi/lo split, v/proj single-bf16 ----
#define WS_QK_HI 0
#define WS_QK_LO 32768
#define WS_V_HI  65536
#define WS_P_HI  81920

// ---- per-batch LDS arena (bytes); 2 arenas = 78336 -> 2 blocks/CU ----
#define OFF_XH   0        // ush [48][128] swz15  x hi        (A -> B)
#define OFF_PH   12288    // ush [48][128] swz15  x+pos hi    (A -> B)
#define OFF_PL   24576    // ush [48][128] swz15  x+pos lo    (A -> B)  ..36864
// aliases (staging dead after B):
#define OFF_KT   0        // ush [128 c][52]      raw k3 bf16 (C -> DE)
#define OFF_VT   13312    // ush [128 d][52]      v bf16      (C -> DE)  ..26624
#define OFF_QO   26624    // ush rows 0..35 [128] swz15  q3 then O (C->DE->G)
                          // G pad-reads rows 36..47 -> bytes < 38912 (garbage, finite, discarded)
#define OFF_MASK 38912    // f32 [48]
#define OFF_INN  39104    // f32
#define AST      39168    // arena stride; 2 x 39168 = 78336

__device__ inline uint bfh(float f) {
    __bf16 h = (__bf16)f;
    return (uint)(*(const ushort*)&h);
}
__device__ inline uint bfl(float f) {
    float hf = (float)((__bf16)f);
    __bf16 l = (__bf16)(f - hf);
    return (uint)(*(const ushort*)&l);
}
__device__ inline uint pk2h(float a, float b) { return bfh(a) | (bfh(b) << 16); }
__device__ inline uint pk2l(float a, float b) { return bfl(a) | (bfl(b) << 16); }

union U8 { bf16x8 v; uint u[4]; };

// ---------------- pre-kernel: weights -> frag-ordered bf16 in ws ----------------
__global__ __launch_bounds__(256)
void prep_frags(const float* __restrict__ qk_w, const float* __restrict__ v_w,
                const float* __restrict__ proj_w, ushort* __restrict__ ws)
{
    int e = blockIdx.x * 256 + threadIdx.x;          // 0..65535
    const float* W; int N; int idx; int hi_off; int lo_off;
    if (e < 32768)      { W = qk_w;   N = 256; hi_off = WS_QK_HI; lo_off = WS_QK_LO; idx = e; }
    else if (e < 49152) { W = v_w;    N = 128; hi_off = WS_V_HI;  lo_off = -1;       idx = e - 32768; }
    else                { W = proj_w; N = 128; hi_off = WS_P_HI;  lo_off = -1;       idx = e - 49152; }
    int j    = idx & 7;
    int lane = (idx >> 3) & 63;
    int ks   = (idx >> 9) & 3;
    int ct   = idx >> 11;
    int col  = ct * 16 + (lane & 15);
    int k    = ks * 32 + (lane >> 4) * 8 + j;
    float v  = W[k * N + col];
    ws[hi_off + idx] = (ushort)bfh(v);
    if (lo_off >= 0) ws[lo_off + idx] = (ushort)bfl(v);
}

// ------- main: 512 thr = 8 waves (wave = head); 2-batch skewed pipeline -------
__global__ __launch_bounds__(512, 4)
void fla_mfma(const float* __restrict__ x, const float* __restrict__ pos,
              const float* __restrict__ mask, const float* __restrict__ qk_b,
              const float* __restrict__ v_b, const float* __restrict__ proj_b,
              const int* __restrict__ vox, const ushort* __restrict__ ws,
              float* __restrict__ out)
{
    __shared__ __align__(16) char lds[2][AST];
    const int t = threadIdx.x;
    const int lane = t & 63;
    const int wv = t >> 6;                           // wave = head
    const int  rsel = lane & 15;
    const int  grp  = lane >> 4;
    const uint kgrp = (uint)grp * 8u;
    const uint sw   = ((uint)rsel) << 4;             // row&15 swizzle on frag reads

    const int b0 = blockIdx.x * 2;
    const int b1 = b0 + 1;

    const int   c16 = wv * 16 + rsel;
    const float qb = qk_b[c16];
    const float kb = qk_b[Cc + c16];
    const float vb = v_b[c16];
    const float pb = proj_b[c16];

    // -------- Phase A: stage x(hi), (x+pos)(hi,lo), mask, inn (immediate) --------
    auto PA = [&](int ar, int bb) {
        char* L = lds[ar];
        const float* xg = x + (size_t)bb * (Nn * Cc);
        const float* pg = pos + (size_t)bb * (Nn * Cc);
        auto put = [&](int idx) {
            int n = idx >> 5, c4 = (idx & 31) << 2;
            float4 xv = *(const float4*)(xg + n * Cc + c4);
            float4 pv = *(const float4*)(pg + n * Cc + c4);
            float s0 = xv.x + pv.x, s1 = xv.y + pv.y;
            float s2 = xv.z + pv.z, s3 = xv.w + pv.w;
            uint ba = (uint)n * 256u + (((uint)(c4 * 2)) ^ (((uint)n & 15u) << 4));
            *(uint2*)(L + OFF_XH + ba) = make_uint2(pk2h(xv.x, xv.y), pk2h(xv.z, xv.w));
            *(uint2*)(L + OFF_PH + ba) = make_uint2(pk2h(s0, s1), pk2h(s2, s3));
            *(uint2*)(L + OFF_PL + ba) = make_uint2(pk2l(s0, s1), pk2l(s2, s3));
        };
        put(t);
        put(t + 512);
        if (t < 128) put(t + 1024);                  // 36 rows x 32 float4 = 1152
        float mvv = (t < Nn) ? mask[(size_t)bb * Nn + t] : 0.f;
        if (t < 48) ((float*)(L + OFF_MASK))[t] = mvv;
        if (wv == 0) {                               // inn via wave-0 butterfly
            float s = mvv;                           // lanes >= 36 hold 0
            s += __shfl_xor(s, 1);  s += __shfl_xor(s, 2);
            s += __shfl_xor(s, 4);  s += __shfl_xor(s, 8);
            s += __shfl_xor(s, 16); s += __shfl_xor(s, 32);
            if (lane == 0) *(float*)(L + OFF_INN) = 1.f / (s + EPSf);
        }
    };

    // -------- Phase B: q,k (split-bf16) + v (single-bf16) tiles of head wv --------
    auto PB = [&](int ar, f32x4 (&accQ)[3], f32x4 (&accK)[3], f32x4 (&accV)[3]) {
        char* L = lds[ar];
        #pragma unroll
        for (int rt = 0; rt < 3; ++rt) {
            accQ[rt] = (f32x4){0.f, 0.f, 0.f, 0.f};
            accK[rt] = (f32x4){0.f, 0.f, 0.f, 0.f};
            accV[rt] = (f32x4){0.f, 0.f, 0.f, 0.f};
        }
        #pragma unroll
        for (int ks = 0; ks < 4; ++ks) {
            uint ka = (((uint)(ks * 32) + kgrp) * 2u) ^ sw;
            bf16x8 ph[3], pl[3];
            #pragma unroll
            for (int rt = 0; rt < 3; ++rt) {
                uint ba = (uint)(rt * 16 + rsel) * 256u + ka;
                ph[rt] = *(const bf16x8*)(L + OFF_PH + ba);
                pl[rt] = *(const bf16x8*)(L + OFF_PL + ba);
            }
            int fq = ((wv * 4 + ks) * 64 + lane) * 8;
            int fk = (((8 + wv) * 4 + ks) * 64 + lane) * 8;
            bf16x8 bqh = *(const bf16x8*)(ws + WS_QK_HI + fq);
            bf16x8 bql = *(const bf16x8*)(ws + WS_QK_LO + fq);
            bf16x8 bkh = *(const bf16x8*)(ws + WS_QK_HI + fk);
            bf16x8 bkl = *(const bf16x8*)(ws + WS_QK_LO + fk);
            #pragma unroll
            for (int rt = 0; rt < 3; ++rt) {
                accQ[rt] = __builtin_amdgcn_mfma_f32_16x16x32_bf16(ph[rt], bqh, accQ[rt], 0, 0, 0);
                accQ[rt] = __builtin_amdgcn_mfma_f32_16x16x32_bf16(ph[rt], bql, accQ[rt], 0, 0, 0);
                accQ[rt] = __builtin_amdgcn_mfma_f32_16x16x32_bf16(pl[rt], bqh, accQ[rt], 0, 0, 0);
                accK[rt] = __builtin_amdgcn_mfma_f32_16x16x32_bf16(ph[rt], bkh, accK[rt], 0, 0, 0);
                accK[rt] = __builtin_amdgcn_mfma_f32_16x16x32_bf16(ph[rt], bkl, accK[rt], 0, 0, 0);
                accK[rt] = __builtin_amdgcn_mfma_f32_16x16x32_bf16(pl[rt], bkh, accK[rt], 0, 0, 0);
            }
        }
        #pragma unroll
        for (int ks = 0; ks < 4; ++ks) {
            uint ka = (((uint)(ks * 32) + kgrp) * 2u) ^ sw;
            bf16x8 xh[3];
            #pragma unroll
            for (int rt = 0; rt < 3; ++rt)
                xh[rt] = *(const bf16x8*)(L + OFF_XH + (uint)(rt * 16 + rsel) * 256u + ka);
            int fv = ((wv * 4 + ks) * 64 + lane) * 8;
            bf16x8 bvh = *(const bf16x8*)(ws + WS_V_HI + fv);
            #pragma unroll
            for (int rt = 0; rt < 3; ++rt)
                accV[rt] = __builtin_amdgcn_mfma_f32_16x16x32_bf16(xh[rt], bvh, accV[rt], 0, 0, 0);
        }
    };

    // -------- Phase C: q3 -> QO, raw k3 -> KT, v -> VT (all own cols) --------
    auto PC = [&](int ar, f32x4 (&accQ)[3], f32x4 (&accK)[3], f32x4 (&accV)[3]) {
        char* L = lds[ar];
        const float* sM = (const float*)(L + OFF_MASK);
        uint cb2 = (uint)(c16 * 2);
        #pragma unroll
        for (int rt = 0; rt < 3; ++rt) {
            #pragma unroll
            for (int r = 0; r < 4; ++r) {
                int row = rt * 16 + grp * 4 + r;
                if (row < Nn) {
                    float q1 = accQ[rt][r] + qb;
                    float q3 = q1 * q1 * q1;
                    uint ba = (uint)row * 256u + (cb2 ^ (((uint)row & 15u) << 4));
                    *(ushort*)(L + OFF_QO + ba) = (ushort)bfh(q3);
                }
            }
        }
        #pragma unroll
        for (int rt = 0; rt < 3; ++rt) {
            float k3v[4];
            #pragma unroll
            for (int r = 0; r < 4; ++r) {
                int row = rt * 16 + grp * 4 + r;
                float k1 = (accK[rt][r] + kb) * sM[row];
                float k3 = k1 * k1 * k1;
                k3v[r] = (rt == 2 && grp != 0) ? 0.f : k3;       // pad rows exact 0
            }
            uint addr = OFF_KT + (uint)(c16 * 52 + rt * 16 + grp * 4) * 2u;
            *(uint2*)(L + addr) = make_uint2(pk2h(k3v[0], k3v[1]), pk2h(k3v[2], k3v[3]));
        }
        #pragma unroll
        for (int rt = 0; rt < 3; ++rt) {
            float a0 = accV[rt][0] + vb, a1 = accV[rt][1] + vb;
            float a2 = accV[rt][2] + vb, a3 = accV[rt][3] + vb;
            if (rt == 2 && grp != 0) { a0 = 0.f; a1 = 0.f; a2 = 0.f; a3 = 0.f; }
            uint addr = OFF_VT + (uint)(c16 * 52 + rt * 16 + grp * 4) * 2u;
            *(uint2*)(L + addr) = make_uint2(pk2h(a0, a1), pk2h(a2, a3));
        }
    };

    // -------- Phase DE: kv in registers; out -> QO (own cols) --------
    auto PDE = [&](int ar) {
        char* L = lds[ar];
        f32x4 kvacc;
        {
            uint a0 = OFF_KT + (uint)(c16 * 52 + grp * 8) * 2u;
            uint b0_ = OFF_VT + (uint)(c16 * 52 + grp * 8) * 2u;
            bf16x8 kA0 = *(const bf16x8*)(L + a0);
            bf16x8 vB0 = *(const bf16x8*)(L + b0_);
            U8 kA1, vB1;
            kA1.u[0] = kA1.u[1] = kA1.u[2] = kA1.u[3] = 0u;
            vB1.u[0] = vB1.u[1] = vB1.u[2] = vB1.u[3] = 0u;
            if (grp < 2) {                           // n = 32 + grp*8 .. +7
                kA1.v = *(const bf16x8*)(L + a0 + 64);
                vB1.v = *(const bf16x8*)(L + b0_ + 64);
            }
            float s = 0.f;
            #pragma unroll
            for (int j = 0; j < 8; ++j) { float q = (float)kA0[j]; s += q * q; }
            #pragma unroll
            for (int j = 0; j < 8; ++j) { float q = (float)kA1.v[j]; s += q * q; }
            s += __shfl_xor(s, 16);
            s += __shfl_xor(s, 32);
            float invkn = 1.f / (EPSf + sqrtf(s));

            kvacc = (f32x4){0.f, 0.f, 0.f, 0.f};
            kvacc = __builtin_amdgcn_mfma_f32_16x16x32_bf16(kA0, vB0, kvacc, 0, 0, 0);
            kvacc = __builtin_amdgcn_mfma_f32_16x16x32_bf16(kA1.v, vB1.v, kvacc, 0, 0, 0);
            #pragma unroll
            for (int r = 0; r < 4; ++r)
                kvacc[r] *= __shfl(invkn, grp * 4 + r);
        }
        {
            float bv[8];
            #pragma unroll
            for (int j = 0; j < 8; ++j)
                bv[j] = __shfl(kvacc[j & 3], rsel + 16 * (2 * grp + (j >> 2)));
            if (grp >= 2) {
                #pragma unroll
                for (int j = 0; j < 8; ++j) bv[j] = 0.f;
            }
            U8 bkv;
            bkv.u[0] = pk2h(bv[0], bv[1]); bkv.u[1] = pk2h(bv[2], bv[3]);
            bkv.u[2] = pk2h(bv[4], bv[5]); bkv.u[3] = pk2h(bv[6], bv[7]);

            float inn = *(const float*)(L + OFF_INN);
            U8 aq[3];
            #pragma unroll
            for (int rt = 0; rt < 3; ++rt) {
                int row = rt * 16 + rsel;
                aq[rt].u[0] = aq[rt].u[1] = aq[rt].u[2] = aq[rt].u[3] = 0u;
                if (grp < 2 && row < Nn)
                    aq[rt].v = *(const bf16x8*)(L + OFF_QO + (uint)row * 256u +
                                                (((uint)(wv * 32 + grp * 16)) ^ sw));
            }
            f32x4 oacc[3];
            float invn[3];
            #pragma unroll
            for (int rt = 0; rt < 3; ++rt) {
                float s = 0.f;
                #pragma unroll
                for (int j = 0; j < 8; ++j) { float q = (float)aq[rt].v[j]; s += q * q; }
                s += __shfl_xor(s, 16);              // lanes 0..15 hold full row sum
                invn[rt] = 1.f / (EPSf + sqrtf(s));
                f32x4 o = (f32x4){0.f, 0.f, 0.f, 0.f};
                o = __builtin_amdgcn_mfma_f32_16x16x32_bf16(aq[rt].v, bkv.v, o, 0, 0, 0);
                oacc[rt] = o;
            }
            uint cb2 = (uint)(c16 * 2);
            #pragma unroll
            for (int rt = 0; rt < 3; ++rt) {
                #pragma unroll
                for (int r = 0; r < 4; ++r) {
                    int rr = grp * 4 + r;
                    int row = rt * 16 + rr;
                    if (row < Nn) {
                        float fac = __shfl(invn[rt], rr) * inn;
                        float val = oacc[rt][r] * fac;
                        uint ba = (uint)row * 256u + (cb2 ^ (((uint)row & 15u) << 4));
                        *(ushort*)(L + OFF_QO + ba) = (ushort)bfh(val);
                    }
                }
            }
        }
    };

    // -------- Phase G: proj GEMM (own out-cols, reads all O) + voxel scatter --------
    auto PG = [&](int ar, int bb) {
        char* L = lds[ar];
        f32x4 accP[3];
        #pragma unroll
        for (int rt = 0; rt < 3; ++rt) accP[rt] = (f32x4){0.f, 0.f, 0.f, 0.f};
        #pragma unroll
        for (int ks = 0; ks < 4; ++ks) {
            uint ka = (((uint)(ks * 32) + kgrp) * 2u) ^ sw;
            bf16x8 oa[3];
            #pragma unroll
            for (int rt = 0; rt < 3; ++rt)
                oa[rt] = *(const bf16x8*)(L + OFF_QO + (uint)(rt * 16 + rsel) * 256u + ka);
            int fp = ((wv * 4 + ks) * 64 + lane) * 8;
            bf16x8 bp = *(const bf16x8*)(ws + WS_P_HI + fp);
            #pragma unroll
            for (int rt = 0; rt < 3; ++rt)
                accP[rt] = __builtin_amdgcn_mfma_f32_16x16x32_bf16(oa[rt], bp, accP[rt], 0, 0, 0);
        }
        const int* voxb = vox + (size_t)bb * Nn;
        #pragma unroll
        for (int rt = 0; rt < 3; ++rt) {
            #pragma unroll
            for (int r = 0; r < 4; ++r) {
                int row = rt * 16 + grp * 4 + r;
                if (row < Nn)
                    out[(size_t)voxb[row] * Cc + c16] = accP[rt][r] + pb;
            }
        }
    };

    // ---------------- skewed 2-batch pipeline (6 intervals, 5 barriers) ----------------
    f32x4 aQ0[3], aK0[3], aV0[3];
    f32x4 aQ1[3], aK1[3], aV1[3];

    PA(0, b0);                               // I1
    __syncthreads();
    PB(0, aQ0, aK0, aV0);                    // I2: MFMA(b0) + stage(b1)
    PA(1, b1);
    __syncthreads();
    PC(0, aQ0, aK0, aV0);                    // I3: VALU(b0) + MFMA(b1)
    PB(1, aQ1, aK1, aV1);
    __syncthreads();
    PDE(0);                                  // I4: MFMA/shfl(b0) + VALU(b1)
    PC(1, aQ1, aK1, aV1);
    __syncthreads();
    PG(0, b0);                               // I5: global(b0) + MFMA/shfl(b1)
    PDE(1);
    __syncthreads();
    PG(1, b1);                               // I6
}

extern "C" void kernel_launch(void* const* d_in, const int* in_sizes, int n_in,
                              void* d_out, int out_size, void* d_ws, size_t ws_size,
                              hipStream_t stream) {
    (void)in_sizes; (void)n_in; (void)out_size; (void)ws_size;
    const float* x      = (const float*)d_in[0];
    const float* pos    = (const float*)d_in[1];
    const float* mask   = (const float*)d_in[2];
    const float* qk_w   = (const float*)d_in[3];
    const float* qk_b   = (const float*)d_in[4];
    const float* v_w    = (const float*)d_in[5];
    const float* v_b    = (const float*)d_in[6];
    const float* proj_w = (const float*)d_in[7];
    const float* proj_b = (const float*)d_in[8];
    // d_in[9] = coords (unused)
    const int*   vox    = (const int*)d_in[10];
    ushort* ws = (ushort*)d_ws;            // 192 KiB scratch used
    float* outp = (float*)d_out;

    hipLaunchKernelGGL(prep_frags, dim3(256), dim3(256), 0, stream, qk_w, v_w, proj_w, ws);
    hipLaunchKernelGGL(fla_mfma, dim3(Bdim / 2), dim3(512), 0, stream,
                       x, pos, mask, qk_b, v_b, proj_b, vox, ws, outp);
}

// Round 14
// 218.174 us; speedup vs baseline: 2.4248x; 1.0290x over previous
//
#include <hip/hip_runtime.h>

typedef __bf16 bf16x8 __attribute__((ext_vector_type(8)));
typedef float f32x4 __attribute__((ext_vector_type(4)));

#define Bdim 8192
#define Nn 36
#define Cc 128
#define EPSf 1e-4f

// ---- d_ws layout (ushort elements): qk hi/lo split, v/proj single-bf16 ----
#define WS_QK_HI 0
#define WS_QK_LO 32768
#define WS_V_HI  65536
#define WS_P_HI  81920

// ---- per-batch LDS arena (byte offsets); two arenas per block ----
#define OFF_XH   0        // ush [48][128] swz15  x hi          (A->B)
#define OFF_PH   12288    // ush [48][128] swz15  x+pos hi      (A->B)
#define OFF_PL   24576    // ush [48][128] swz15  x+pos lo      (A->B) ..36864
#define OFF_KT   0        // ush [128 c][50]      raw k3 bf16   (C->D) over XH
#define OFF_VT   12800    // ush [128 d][50]      v bf16        (C->D)
#define OFF_QH   25600    // ush [36][128] swz15  raw q3 bf16   (C->E)
#define OFF_KV   34816    // ush [8 h][16 d][20 c] kv-hat bf16  (D->E)
#define OFF_O    0        // ush [48][128] swz15  attn out bf16 (E->G) over KT
#define OFF_MASK 39936    // f32 [48]
#define OFF_VOX  40128    // int [36]
#define OFF_INN  40272    // f32
#define AST      40288    // arena stride; 2 arenas = 80576 B -> 2 blocks/CU

__device__ inline uint bfh(float f) {
    __bf16 h = (__bf16)f;
    return (uint)(*(const ushort*)&h);
}
__device__ inline uint bfl(float f) {
    float hf = (float)((__bf16)f);
    __bf16 l = (__bf16)(f - hf);
    return (uint)(*(const ushort*)&l);
}
__device__ inline uint pk2h(float a, float b) { return bfh(a) | (bfh(b) << 16); }
__device__ inline uint pk2l(float a, float b) { return bfl(a) | (bfl(b) << 16); }

union U8 { bf16x8 v; uint u[4]; };

// ---------------- pre-kernel: weights -> frag-ordered bf16 in ws ----------------
__global__ __launch_bounds__(256)
void prep_frags(const float* __restrict__ qk_w, const float* __restrict__ v_w,
                const float* __restrict__ proj_w, ushort* __restrict__ ws)
{
    int e = blockIdx.x * 256 + threadIdx.x;          // 0..65535
    const float* W; int N; int idx; int hi_off; int lo_off;
    if (e < 32768)      { W = qk_w;   N = 256; hi_off = WS_QK_HI; lo_off = WS_QK_LO; idx = e; }
    else if (e < 49152) { W = v_w;    N = 128; hi_off = WS_V_HI;  lo_off = -1;       idx = e - 32768; }
    else                { W = proj_w; N = 128; hi_off = WS_P_HI;  lo_off = -1;       idx = e - 49152; }
    int j    = idx & 7;
    int lane = (idx >> 3) & 63;
    int ks   = (idx >> 9) & 3;
    int ct   = idx >> 11;
    int col  = ct * 16 + (lane & 15);
    int k    = ks * 32 + (lane >> 4) * 8 + j;
    float v  = W[k * N + col];
    ws[hi_off + idx] = (ushort)bfh(v);
    if (lo_off >= 0) ws[lo_off + idx] = (ushort)bfl(v);
}

// ---------------- main kernel: one block = 2 batches, skewed pipeline ----------------
__global__ __launch_bounds__(512, 4)
void fla_mfma(const float* __restrict__ x, const float* __restrict__ pos,
              const float* __restrict__ mask, const float* __restrict__ qk_b,
              const float* __restrict__ v_b, const float* __restrict__ proj_b,
              const int* __restrict__ vox, const ushort* __restrict__ ws,
              float* __restrict__ out)
{
    __shared__ __align__(16) char lds[2][AST];
    const int t = threadIdx.x;
    const int lane = t & 63;
    const int wv = t >> 6;                           // 8 waves

    const int  rsel = lane & 15;
    const int  grp  = lane >> 4;
    const uint kgrp = (uint)grp * 8u;
    const uint sw   = ((uint)rsel) << 4;             // row&15 swizzle on frag reads

    const int b0 = blockIdx.x * 2;
    const int b1 = b0 + 1;

    // ---------------- Phase A: stage x(hi), (x+pos)(hi,lo), scalars ----------------
    auto PA = [&](int ar, int bb) {
        char* L = lds[ar];
        const float* xg = x + (size_t)bb * (Nn * Cc);
        const float* pg = pos + (size_t)bb * (Nn * Cc);
        auto put = [&](int idx) {
            int n = idx >> 5;
            int c4 = (idx & 31) << 2;
            float4 xv = *(const float4*)(xg + n * Cc + c4);
            float4 pv = *(const float4*)(pg + n * Cc + c4);
            float s0 = xv.x + pv.x, s1 = xv.y + pv.y;
            float s2 = xv.z + pv.z, s3 = xv.w + pv.w;
            uint ba = (uint)n * 256u + (((uint)(c4 * 2)) ^ (((uint)n & 15u) << 4));
            *(uint2*)(L + OFF_XH + ba) = make_uint2(pk2h(xv.x, xv.y), pk2h(xv.z, xv.w));
            *(uint2*)(L + OFF_PH + ba) = make_uint2(pk2h(s0, s1), pk2h(s2, s3));
            *(uint2*)(L + OFF_PL + ba) = make_uint2(pk2l(s0, s1), pk2l(s2, s3));
        };
        put(t);
        put(t + 512);
        if (t < 128) put(t + 1024);                   // 36 rows x 32 float4 = 1152
        if (t < 48) ((float*)(L + OFF_MASK))[t] = (t < Nn) ? mask[(size_t)bb * Nn + t] : 0.f;
        if (t >= 64 && t < 64 + Nn) ((int*)(L + OFF_VOX))[t - 64] = vox[(size_t)bb * Nn + (t - 64)];
        if (t == 128) {
            float s = 0.f;
            for (int n = 0; n < Nn; ++n) s += mask[(size_t)bb * Nn + n];
            *(float*)(L + OFF_INN) = 1.f / (s + EPSf);
        }
    };

    // ---------------- Phase B: v GEMM (single-bf16) + qk GEMM (split-bf16) ----------
    auto PB = [&](int ar, f32x4 (&accV)[3], f32x4 (&accQ)[3][2]) {
        char* L = lds[ar];
        #pragma unroll
        for (int rt = 0; rt < 3; ++rt) {
            accV[rt] = (f32x4){0.f, 0.f, 0.f, 0.f};
            accQ[rt][0] = (f32x4){0.f, 0.f, 0.f, 0.f};
            accQ[rt][1] = (f32x4){0.f, 0.f, 0.f, 0.f};
        }
        __builtin_amdgcn_s_setprio(1);                // T5: favor MFMA burst
        #pragma unroll
        for (int ks = 0; ks < 4; ++ks) {              // v: A = x(hi) only
            uint ka = (((uint)(ks * 32) + kgrp) * 2u) ^ sw;
            bf16x8 xh[3];
            #pragma unroll
            for (int rt = 0; rt < 3; ++rt)
                xh[rt] = *(const bf16x8*)(L + OFF_XH + (uint)(rt * 16 + rsel) * 256u + ka);
            int f = ((wv * 4 + ks) * 64 + lane) * 8;
            bf16x8 bvh = *(const bf16x8*)(ws + WS_V_HI + f);
            #pragma unroll
            for (int rt = 0; rt < 3; ++rt)
                accV[rt] = __builtin_amdgcn_mfma_f32_16x16x32_bf16(xh[rt], bvh, accV[rt], 0, 0, 0);
        }
        #pragma unroll
        for (int ks = 0; ks < 4; ++ks) {              // qk: split 3-product
            uint ka = (((uint)(ks * 32) + kgrp) * 2u) ^ sw;
            bf16x8 ph[3], pl[3];
            #pragma unroll
            for (int rt = 0; rt < 3; ++rt) {
                uint ba = (uint)(rt * 16 + rsel) * 256u + ka;
                ph[rt] = *(const bf16x8*)(L + OFF_PH + ba);
                pl[rt] = *(const bf16x8*)(L + OFF_PL + ba);
            }
            #pragma unroll
            for (int ci = 0; ci < 2; ++ci) {
                int f = (((wv * 2 + ci) * 4 + ks) * 64 + lane) * 8;
                bf16x8 bh = *(const bf16x8*)(ws + WS_QK_HI + f);
                bf16x8 bl = *(const bf16x8*)(ws + WS_QK_LO + f);
                #pragma unroll
                for (int rt = 0; rt < 3; ++rt) {
                    accQ[rt][ci] = __builtin_amdgcn_mfma_f32_16x16x32_bf16(ph[rt], bh, accQ[rt][ci], 0, 0, 0);
                    accQ[rt][ci] = __builtin_amdgcn_mfma_f32_16x16x32_bf16(ph[rt], bl, accQ[rt][ci], 0, 0, 0);
                    accQ[rt][ci] = __builtin_amdgcn_mfma_f32_16x16x32_bf16(pl[rt], bh, accQ[rt][ci], 0, 0, 0);
                }
            }
        }
        __builtin_amdgcn_s_setprio(0);
    };

    // ---------------- Phase C: epilogues -> VT, QH(raw q3), KT(raw k3) --------------
    auto PC = [&](int ar, f32x4 (&accV)[3], f32x4 (&accQ)[3][2]) {
        char* L = lds[ar];
        const float* sM = (const float*)(L + OFF_MASK);
        {   // v: +bias -> bf16 -> VT[d=col][n] (stride 50)
            int colv = wv * 16 + rsel;
            float vb = v_b[colv];
            #pragma unroll
            for (int rt = 0; rt < 3; ++rt) {
                float a0 = accV[rt][0] + vb, a1 = accV[rt][1] + vb;
                float a2 = accV[rt][2] + vb, a3 = accV[rt][3] + vb;
                uint addr = OFF_VT + (uint)(colv * 50 + rt * 16 + grp * 4) * 2u;
                *(uint2*)(L + addr) = make_uint2(pk2h(a0, a1), pk2h(a2, a3));
            }
        }
        if (wv < 4) {       // q: +bias, cube -> QH scatter (rows<36)
            #pragma unroll
            for (int ci = 0; ci < 2; ++ci) {
                int colq = (wv * 2 + ci) * 16 + rsel;
                float qb = qk_b[colq];
                uint cb2 = (uint)(colq * 2);
                #pragma unroll
                for (int rt = 0; rt < 3; ++rt) {
                    #pragma unroll
                    for (int r = 0; r < 4; ++r) {
                        int row = rt * 16 + grp * 4 + r;
                        if (row < Nn) {
                            float q1 = accQ[rt][ci][r] + qb;
                            float q3 = q1 * q1 * q1;
                            uint ba = (uint)row * 256u + (cb2 ^ (((uint)row & 15u) << 4));
                            *(ushort*)(L + OFF_QH + ba) = (ushort)bfh(q3);
                        }
                    }
                }
            }
        } else {            // k: +bias, *mask, cube -> KT[c=col][n] (stride 50)
            #pragma unroll
            for (int ci = 0; ci < 2; ++ci) {
                int colk = ((wv - 4) * 2 + ci) * 16 + rsel;
                float kb = qk_b[Cc + colk];
                #pragma unroll
                for (int rt = 0; rt < 3; ++rt) {
                    float k3v[4];
                    #pragma unroll
                    for (int r = 0; r < 4; ++r) {
                        int row = rt * 16 + grp * 4 + r;
                        float k1 = (accQ[rt][ci][r] + kb) * sM[row];
                        k3v[r] = k1 * k1 * k1;
                    }
                    uint addr = OFF_KT + (uint)(colk * 50 + rt * 16 + grp * 4) * 2u;
                    *(uint2*)(L + addr) = make_uint2(pk2h(k3v[0], k3v[1]), pk2h(k3v[2], k3v[3]));
                }
            }
        }
    };

    // ---------------- Phase D: kv-hat = invkn[c]*(k3^T @ v), bf16 -> KV[h][d][c] -----
    auto PD = [&](int ar) {
        char* L = lds[ar];
        int col16 = wv * 16 + rsel;                  // c (A-row) and d (B-col) index
        uint a0 = OFF_KT + (uint)(col16 * 50 + grp * 8) * 2u;
        uint b0_ = OFF_VT + (uint)(col16 * 50 + grp * 8) * 2u;
        bf16x8 kA0 = *(const bf16x8*)(L + a0);
        bf16x8 vB0 = *(const bf16x8*)(L + b0_);
        U8 kA1, vB1;
        kA1.u[0] = kA1.u[1] = kA1.u[2] = kA1.u[3] = 0u;
        vB1.u[0] = vB1.u[1] = vB1.u[2] = vB1.u[3] = 0u;
        if (grp < 2) {                               // n = 32 + grp*8 .. +7
            kA1.v = *(const bf16x8*)(L + a0 + 64);
            vB1.v = *(const bf16x8*)(L + b0_ + 64);
        }
        float s = 0.f;
        #pragma unroll
        for (int j = 0; j < 8; ++j) { float q = (float)kA0[j]; s += q * q; }
        #pragma unroll
        for (int j = 0; j < 8; ++j) { float q = (float)kA1.v[j]; s += q * q; }
        s += __shfl_xor(s, 16);
        s += __shfl_xor(s, 32);
        float invkn = 1.f / (EPSf + sqrtf(s));

        f32x4 kvacc = (f32x4){0.f, 0.f, 0.f, 0.f};
        kvacc = __builtin_amdgcn_mfma_f32_16x16x32_bf16(kA0, vB0, kvacc, 0, 0, 0);
        kvacc = __builtin_amdgcn_mfma_f32_16x16x32_bf16(kA1.v, vB1.v, kvacc, 0, 0, 0);

        float f0 = __shfl(invkn, grp * 4 + 0);
        float f1 = __shfl(invkn, grp * 4 + 1);
        float f2 = __shfl(invkn, grp * 4 + 2);
        float f3 = __shfl(invkn, grp * 4 + 3);
        uint addr = OFF_KV + (uint)(wv * 320 + rsel * 20 + grp * 4) * 2u;
        *(uint2*)(L + addr) =
            make_uint2(pk2h(kvacc[0] * f0, kvacc[1] * f1), pk2h(kvacc[2] * f2, kvacc[3] * f3));
    };

    // ---------------- Phase E: out = invn[row]*inn * (q3 @ kv-hat) -> O --------------
    auto PE = [&](int ar) {
        char* L = lds[ar];
        int d = rsel;
        float inn = *(const float*)(L + OFF_INN);
        U8 bkv;
        bkv.u[0] = bkv.u[1] = bkv.u[2] = bkv.u[3] = 0u;
        if (grp < 2)                                  // c = grp*8 + j
            bkv.v = *(const bf16x8*)(L + OFF_KV + (uint)(wv * 320 + d * 20 + grp * 8) * 2u);
        f32x4 oacc[3];
        float invn[3];
        #pragma unroll
        for (int rt = 0; rt < 3; ++rt) {
            int row = rt * 16 + rsel;
            U8 aq;
            aq.u[0] = aq.u[1] = aq.u[2] = aq.u[3] = 0u;
            if (grp < 2 && row < Nn) {
                uint ba = (uint)row * 256u +
                          (((uint)((wv * 16 + grp * 8) * 2)) ^ (((uint)row & 15u) << 4));
                aq.v = *(const bf16x8*)(L + OFF_QH + ba);
            }
            float s = 0.f;
            #pragma unroll
            for (int j = 0; j < 8; ++j) { float q = (float)aq.v[j]; s += q * q; }
            s += __shfl_xor(s, 16);                   // lanes 0..31 hold full row norm
            invn[rt] = 1.f / (EPSf + sqrtf(s));
            f32x4 o = (f32x4){0.f, 0.f, 0.f, 0.f};
            o = __builtin_amdgcn_mfma_f32_16x16x32_bf16(aq.v, bkv.v, o, 0, 0, 0);
            oacc[rt] = o;
        }
        #pragma unroll
        for (int rt = 0; rt < 3; ++rt) {
            #pragma unroll
            for (int r = 0; r < 4; ++r) {
                int rr = grp * 4 + r;
                int row = rt * 16 + rr;
                float fac = __shfl(invn[rt], rr) * inn;
                float val = oacc[rt][r] * fac;
                uint ba = (uint)row * 256u +
                          (((uint)((wv * 16 + d) * 2)) ^ (((uint)row & 15u) << 4));
                if (row < Nn)
                    *(ushort*)(L + OFF_O + ba) = (ushort)bfh(val);
            }
        }
    };

    // ---------------- Phase G: proj GEMM (single-bf16) + scatter ---------------------
    auto PG = [&](int ar) {
        char* L = lds[ar];
        f32x4 accP[3];
        #pragma unroll
        for (int rt = 0; rt < 3; ++rt) accP[rt] = (f32x4){0.f, 0.f, 0.f, 0.f};
        __builtin_amdgcn_s_setprio(1);                // T5
        #pragma unroll
        for (int ks = 0; ks < 4; ++ks) {
            uint ka = (((uint)(ks * 32) + kgrp) * 2u) ^ sw;
            bf16x8 oa[3];
            #pragma unroll
            for (int rt = 0; rt < 3; ++rt)
                oa[rt] = *(const bf16x8*)(L + OFF_O + (uint)(rt * 16 + rsel) * 256u + ka);
            int f = ((wv * 4 + ks) * 64 + lane) * 8;
            bf16x8 bp = *(const bf16x8*)(ws + WS_P_HI + f);
            #pragma unroll
            for (int rt = 0; rt < 3; ++rt)
                accP[rt] = __builtin_amdgcn_mfma_f32_16x16x32_bf16(oa[rt], bp, accP[rt], 0, 0, 0);
        }
        __builtin_amdgcn_s_setprio(0);
        const int* sVx = (const int*)(L + OFF_VOX);
        int col = wv * 16 + rsel;
        float pb = proj_b[col];
        #pragma unroll
        for (int rt = 0; rt < 3; ++rt) {
            #pragma unroll
            for (int r = 0; r < 4; ++r) {
                int row = rt * 16 + grp * 4 + r;
                if (row < Nn)
                    out[(size_t)sVx[row] * Cc + col] = accP[rt][r] + pb;
            }
        }
    };

    // ---------------- skewed 2-batch pipeline (7 intervals, 6 barriers) --------------
    f32x4 accV0[3], accV1[3];
    f32x4 accQ0[3][2], accQ1[3][2];

    // zero-fill pad rows 36..47 of XH/PH/PL in both arenas (once; aliases never
    // re-expose them: O-row pads read by PG land on finite KT data)
    for (int z = t; z < 1152; z += 512) {
        int ar = z / 576;
        int r = z % 576;
        int reg = r / 192;
        int off = (r % 192) * 16;
        char* basep = lds[ar] + (reg == 0 ? OFF_XH : (reg == 1 ? OFF_PH : OFF_PL));
        *(uint4*)(basep + 9216 + off) = make_uint4(0u, 0u, 0u, 0u);
    }
    PA(0, b0);                               // I1
    __syncthreads();
    PB(0, accV0, accQ0);                     // I2: MFMA(b0) + stage(b1)
    PA(1, b1);
    __syncthreads();
    PC(0, accV0, accQ0);                     // I3: VALU(b0) + MFMA(b1)
    PB(1, accV1, accQ1);
    __syncthreads();
    PD(0);                                   // I4: MFMA(b0) + VALU(b1)
    PC(1, accV1, accQ1);
    __syncthreads();
    PE(0);                                   // I5
    PD(1);
    __syncthreads();
    PG(0);                                   // I6: global(b0) + MFMA/VALU(b1)
    PE(1);
    __syncthreads();
    PG(1);                                   // I7
}

extern "C" void kernel_launch(void* const* d_in, const int* in_sizes, int n_in,
                              void* d_out, int out_size, void* d_ws, size_t ws_size,
                              hipStream_t stream) {
    (void)in_sizes; (void)n_in; (void)out_size; (void)ws_size;
    const float* x      = (const float*)d_in[0];
    const float* pos    = (const float*)d_in[1];
    const float* mask   = (const float*)d_in[2];
    const float* qk_w   = (const float*)d_in[3];
    const float* qk_b   = (const float*)d_in[4];
    const float* v_w    = (const float*)d_in[5];
    const float* v_b    = (const float*)d_in[6];
    const float* proj_w = (const float*)d_in[7];
    const float* proj_b = (const float*)d_in[8];
    // d_in[9] = coords (unused)
    const int*   vox    = (const int*)d_in[10];
    ushort* ws = (ushort*)d_ws;            // 192 KiB scratch used
    float* outp = (float*)d_out;

    hipLaunchKernelGGL(prep_frags, dim3(256), dim3(256), 0, stream, qk_w, v_w, proj_w, ws);
    hipLaunchKernelGGL(fla_mfma, dim3(Bdim / 2), dim3(512), 0, stream,
                       x, pos, mask, qk_b, v_b, proj_b, vox, ws, outp);
}